// Round 6
// baseline (883.699 us; speedup 1.0000x reference)
//
#include <hip/hip_runtime.h>
#include <stdint.h>

#define NBATCH 64
#define HH 512
#define WW 512
#define NPIX 262144            // 512*512
#define BINS1 2048             // key bits [31:21]
#define BINS2 2048             // key bits [20:10]
#define BINS3 1024             // key bits [9:0]
#define HGX 32                 // hist blocks per batch
#define HITER (NPIX/4/HGX/256) // float4 iters per hist block (= 8)
#define GGRID (32*NBATCH)      // k_grad grid size

// ---------------- workspace layout (u32 units) ----------------
#define SZ_C1 (2*NBATCH*BINS1)
#define OFF_C1 0
#define OFF_C2 (OFF_C1 + SZ_C1)
#define SZ_C3 (2*NBATCH*BINS3)
#define OFF_C3 (OFF_C2 + SZ_C1)
#define OFF_SUM3 (OFF_C3 + SZ_C3)      // f32 [2*64][1024] level-3 bin sums
#define OFF_STATE (OFF_SUM3 + SZ_C3)
#define ST_N     (OFF_STATE)        // u32 [128] masked count per (tensor,batch)
#define ST_N2    (ST_N + 128)       // u32 [128] #{x > median}
#define ST_B1    (ST_N2 + 128)      // u32 [128]
#define ST_B2    (ST_B1 + 128)      // u32 [128]
#define ST_RANK  (ST_B2 + 128)      // u32 [128]
#define ST_CLT   (ST_RANK + 128)    // u32 [128] count strictly below bucket
#define ST_SHIFT (ST_CLT + 128)     // f32 [128] median
#define ST_SCL   (ST_SHIFT + 128)   // f32 [128] robust scale
#define ST_STOT  (ST_SCL + 128)     // f32 [128] sum of masked x
#define ST_S1    (ST_STOT + 128)    // f32 [128] sum of masked x, level-1 bucket < b1
#define ST_S2    (ST_S1 + 128)      // f32 [128] sum of masked x, bucket==b1, mid < b2
#define ST_TSUM  (ST_S2 + 128)      // f32 [64]  residual sum (trim provably no-op)
#define ST_GSUM  (ST_TSUM + 64)     // f32 [4*64] gradient sums
#define ST_GCNT  (ST_GSUM + 256)    // u32 [4*64] gradient mask counts
#define ST_DONE1 (ST_GCNT + 256)    // u32 [64] last-block tickets (med1)
#define ST_DONE2 (ST_DONE1 + 64)    // u32 [64] (med2)
#define ST_DONE3 (ST_DONE2 + 64)    // u32 [64] (med3)
#define ST_DONEG (ST_DONE3 + 64)    // u32 [1]  (grad)
#define WS_TOTAL (ST_DONEG + 1)

// gradient tile geometry: 128x64 interior, 136x72 loaded (right/bottom halo 8)
#define GTW 128
#define GTH 64
#define GHALO 8
#define GLW (GTW + GHALO)      // 136
#define GLH (GTH + GHALO)      // 72
#define GL4 (GLW/4)            // 34

#define AGL_U(p) __hip_atomic_load((p), __ATOMIC_RELAXED, __HIP_MEMORY_SCOPE_AGENT)
#define AGL_F(p) __hip_atomic_load((p), __ATOMIC_RELAXED, __HIP_MEMORY_SCOPE_AGENT)

// order-preserving float -> u32 key
__device__ __forceinline__ uint32_t fkey(float x) {
    uint32_t u = __float_as_uint(x);
    return (u & 0x80000000u) ? ~u : (u | 0x80000000u);
}
__device__ __forceinline__ float funkey(uint32_t k) {
    return __uint_as_float((k & 0x80000000u) ? (k & 0x7fffffffu) : ~k);
}
__device__ __forceinline__ float norm_diff(float p, float t, float sp, float ivp, float st, float ivt) {
    return (p - sp)*ivp - (t - st)*ivt;
}

// ===== in-kernel radix-select level (runs in the LAST block of each hist pass) =====
// LEVEL 0: median rank init; LEVEL 1: bucket refine; LEVEL 2: final key + MAD scale.
template<int NBINS, int LEVEL>
__device__ void select_level(uint32_t* wu, float* wf,
                             const uint32_t* cnt, const float* sum3, int q) {
    __shared__ uint32_t sc[256];
    __shared__ float ss[256];
    const int tid = threadIdx.x;
    constexpr int bpt = NBINS >> 8;
    const uint32_t* c = cnt + (size_t)q*NBINS + (size_t)tid*bpt;
    uint32_t cl[bpt]; float sl[bpt];
    uint32_t tcnt = 0; float tfs = 0.f;
#pragma unroll
    for (int j = 0; j < bpt; ++j) { cl[j] = AGL_U(&c[j]); tcnt += cl[j]; }
    if (LEVEL == 2) {
        const float* s3 = sum3 + (size_t)q*NBINS + (size_t)tid*bpt;
#pragma unroll
        for (int j = 0; j < bpt; ++j) { sl[j] = AGL_F(&s3[j]); tfs += sl[j]; }
    }
    __syncthreads();                 // protect sc/ss reuse across sequential calls
    sc[tid] = tcnt; ss[tid] = tfs;
    __syncthreads();
    for (int off = 1; off < 256; off <<= 1) {
        uint32_t u = 0; float f = 0.f;
        if (tid >= off) { u = sc[tid-off]; f = ss[tid-off]; }
        __syncthreads();
        if (tid >= off) { sc[tid] += u; ss[tid] += f; }
        __syncthreads();
    }
    const uint32_t total = sc[255];
    const uint32_t excl = sc[tid] - tcnt;
    const float exclS = ss[tid] - tfs;

    uint32_t r;
    if (LEVEL == 0) {
        if (tid == 0) wu[ST_N+q] = total;
        r = total ? (total - 1u) / 2u : 0u;   // lower median rank
    } else {
        r = wu[ST_RANK+q];
    }
    __syncthreads();

    if (total > 0u && excl <= r && r < excl + tcnt) {
        uint32_t cum = excl; float fs = exclS;
#pragma unroll
        for (int j = 0; j < bpt; ++j) {
            uint32_t cj = cl[j];
            if (r < cum + cj) {
                uint32_t bidx = (uint32_t)(tid*bpt + j);
                if (LEVEL == 0) {
                    wu[ST_B1+q] = bidx; wu[ST_RANK+q] = r - cum; wu[ST_CLT+q] = cum;
                } else if (LEVEL == 1) {
                    wu[ST_B2+q] = bidx; wu[ST_RANK+q] = r - cum; wu[ST_CLT+q] += cum;
                } else {
                    uint32_t key = (wu[ST_B1+q] << 21) | (wu[ST_B2+q] << 10) | bidx;
                    float m = funkey(key);                     // exact lower median
                    uint32_t n = wu[ST_N+q];
                    uint32_t c_le = wu[ST_CLT+q] + cum + cj;   // #{x <= m}
                    float S_le = AGL_F(&wf[ST_S1+q]) + AGL_F(&wf[ST_S2+q]) + fs + sl[j];
                    float madsum = (float)(2u*c_le - n) * m + AGL_F(&wf[ST_STOT+q]) - 2.f*S_le;
                    float scale = madsum / (float)(n ? n : 1u);
                    if (!(scale > 0.f)) scale = 1.f;           // ref: scale==0 -> 1
                    wf[ST_SHIFT+q] = m; wf[ST_SCL+q] = scale;
                    wu[ST_N2+q] = n - c_le;                    // #{x > median}
                }
                break;
            }
            cum += cj;
            if (LEVEL == 2) fs += sl[j];
        }
    }
    if (tid == 0 && total == 0u) {  // degenerate guard
        if (LEVEL == 0)      { wu[ST_B1+q]=0; wu[ST_RANK+q]=0; wu[ST_CLT+q]=0; }
        else if (LEVEL == 1) { wu[ST_B2+q]=0; }
        else                 { wf[ST_SHIFT+q]=0.f; wf[ST_SCL+q]=1.f; wu[ST_N2+q]=0u; }
    }
}

// ===== medhist1: level-1 counts (mask = tgt>0) + streaming S_tot; last block selects =====
__global__ __launch_bounds__(256) void k_medhist1(const float* __restrict__ pred, const float* __restrict__ tgt,
                                                  uint32_t* __restrict__ cnt, float* __restrict__ stot,
                                                  uint32_t* wu, float* wf, uint32_t* done) {
    __shared__ uint32_t cP[BINS1], cT[BINS1];
    __shared__ float redP[4], redT[4];
    __shared__ uint32_t s_tick;
    const int tid = threadIdx.x;
    for (int i = tid; i < BINS1; i += 256) { cP[i]=0u; cT[i]=0u; }
    __syncthreads();
    const int b = blockIdx.y;
    const float4* p4 = (const float4*)pred;
    const float4* t4 = (const float4*)tgt;
    size_t base = (size_t)b*(NPIX/4) + (size_t)blockIdx.x*(NPIX/4/HGX);
    float aP = 0.f, aT = 0.f;
    for (int it = 0; it < HITER; it += 2) {   // unroll 2: 4 loads in flight
        size_t i0 = base + (size_t)it*256 + tid;
        float4 pv0 = p4[i0], tv0 = t4[i0];
        float4 pv1 = p4[i0+256], tv1 = t4[i0+256];
        float pa[8] = {pv0.x,pv0.y,pv0.z,pv0.w, pv1.x,pv1.y,pv1.z,pv1.w};
        float ta[8] = {tv0.x,tv0.y,tv0.z,tv0.w, tv1.x,tv1.y,tv1.z,tv1.w};
#pragma unroll
        for (int j = 0; j < 8; ++j) {
            if (ta[j] > 0.f) {
                atomicAdd(&cP[fkey(pa[j]) >> 21], 1u);
                atomicAdd(&cT[fkey(ta[j]) >> 21], 1u);
                aP += pa[j]; aT += ta[j];
            }
        }
    }
    const int lane = tid & 63, wv = tid >> 6;
    for (int off = 32; off; off >>= 1) { aP += __shfl_down(aP, off, 64); aT += __shfl_down(aT, off, 64); }
    if (lane == 0) { redP[wv] = aP; redT[wv] = aT; }
    __syncthreads();
    if (tid == 0) atomicAdd(&stot[b],        redP[0]+redP[1]+redP[2]+redP[3]);
    if (tid == 1) atomicAdd(&stot[NBATCH+b], redT[0]+redT[1]+redT[2]+redT[3]);
    for (int i = tid; i < BINS1; i += 256) {
        if (cP[i]) atomicAdd(&cnt[(size_t)b*BINS1+i], cP[i]);
        if (cT[i]) atomicAdd(&cnt[(size_t)(NBATCH+b)*BINS1+i], cT[i]);
    }
    // ---- last block of this batch runs level-0 select for both tensors ----
    __threadfence();
    if (tid == 0) s_tick = atomicAdd(&done[b], 1u);
    __syncthreads();
    if (s_tick == HGX-1) {
        __threadfence();
        select_level<BINS1,0>(wu, wf, cnt, nullptr, b);
        select_level<BINS1,0>(wu, wf, cnt, nullptr, NBATCH+b);
    }
}

// ===== medhist2: level-2 counts + streaming S1; last block selects =====
__global__ __launch_bounds__(256) void k_medhist2(const float* __restrict__ pred, const float* __restrict__ tgt,
                                                  const uint32_t* __restrict__ b1arr,
                                                  uint32_t* __restrict__ cnt, float* __restrict__ s1arr,
                                                  uint32_t* wu, float* wf, uint32_t* done) {
    __shared__ uint32_t cP[BINS2], cT[BINS2];
    __shared__ float redP[4], redT[4];
    __shared__ uint32_t s_tick;
    const int tid = threadIdx.x;
    for (int i = tid; i < BINS2; i += 256) { cP[i]=0u; cT[i]=0u; }
    __syncthreads();
    const int b = blockIdx.y;
    const uint32_t b1p = b1arr[b], b1t = b1arr[NBATCH+b];
    const float4* p4 = (const float4*)pred;
    const float4* t4 = (const float4*)tgt;
    size_t base = (size_t)b*(NPIX/4) + (size_t)blockIdx.x*(NPIX/4/HGX);
    float aP = 0.f, aT = 0.f;
    for (int it = 0; it < HITER; it += 2) {
        size_t i0 = base + (size_t)it*256 + tid;
        float4 pv0 = p4[i0], tv0 = t4[i0];
        float4 pv1 = p4[i0+256], tv1 = t4[i0+256];
        float pa[8] = {pv0.x,pv0.y,pv0.z,pv0.w, pv1.x,pv1.y,pv1.z,pv1.w};
        float ta[8] = {tv0.x,tv0.y,tv0.z,tv0.w, tv1.x,tv1.y,tv1.z,tv1.w};
#pragma unroll
        for (int j = 0; j < 8; ++j) {
            if (ta[j] > 0.f) {
                uint32_t kp = fkey(pa[j]), kt = fkey(ta[j]);
                uint32_t hp = kp >> 21, ht = kt >> 21;
                if (hp == b1p) atomicAdd(&cP[(kp>>10)&2047u], 1u);
                else if (hp < b1p) aP += pa[j];
                if (ht == b1t) atomicAdd(&cT[(kt>>10)&2047u], 1u);
                else if (ht < b1t) aT += ta[j];
            }
        }
    }
    const int lane = tid & 63, wv = tid >> 6;
    for (int off = 32; off; off >>= 1) { aP += __shfl_down(aP, off, 64); aT += __shfl_down(aT, off, 64); }
    if (lane == 0) { redP[wv] = aP; redT[wv] = aT; }
    __syncthreads();
    if (tid == 0) atomicAdd(&s1arr[b],        redP[0]+redP[1]+redP[2]+redP[3]);
    if (tid == 1) atomicAdd(&s1arr[NBATCH+b], redT[0]+redT[1]+redT[2]+redT[3]);
    for (int i = tid; i < BINS2; i += 256) {
        if (cP[i]) atomicAdd(&cnt[(size_t)b*BINS2+i], cP[i]);
        if (cT[i]) atomicAdd(&cnt[(size_t)(NBATCH+b)*BINS2+i], cT[i]);
    }
    __threadfence();
    if (tid == 0) s_tick = atomicAdd(&done[b], 1u);
    __syncthreads();
    if (s_tick == HGX-1) {
        __threadfence();
        select_level<BINS2,1>(wu, wf, cnt, nullptr, b);
        select_level<BINS2,1>(wu, wf, cnt, nullptr, NBATCH+b);
    }
}

// ===== medhist3: level-3 counts + sums + streaming S2; last block selects + MAD scale =====
__global__ __launch_bounds__(256) void k_medhist3(const float* __restrict__ pred, const float* __restrict__ tgt,
                                                  const uint32_t* __restrict__ b1arr, const uint32_t* __restrict__ b2arr,
                                                  uint32_t* __restrict__ cnt, float* __restrict__ sum3,
                                                  float* __restrict__ s2arr,
                                                  uint32_t* wu, float* wf, uint32_t* done) {
    __shared__ uint32_t cP[BINS3], cT[BINS3];
    __shared__ float sSP[BINS3], sST[BINS3];
    __shared__ float redP[4], redT[4];
    __shared__ uint32_t s_tick;
    const int tid = threadIdx.x;
    for (int i = tid; i < BINS3; i += 256) { cP[i]=0u; cT[i]=0u; sSP[i]=0.f; sST[i]=0.f; }
    __syncthreads();
    const int b = blockIdx.y;
    const uint32_t b1p = b1arr[b], b1t = b1arr[NBATCH+b];
    const uint32_t t22p = (b1p<<11) | b2arr[b];
    const uint32_t t22t = (b1t<<11) | b2arr[NBATCH+b];
    const float4* p4 = (const float4*)pred;
    const float4* t4 = (const float4*)tgt;
    size_t base = (size_t)b*(NPIX/4) + (size_t)blockIdx.x*(NPIX/4/HGX);
    float aP = 0.f, aT = 0.f;
    for (int it = 0; it < HITER; it += 2) {
        size_t i0 = base + (size_t)it*256 + tid;
        float4 pv0 = p4[i0], tv0 = t4[i0];
        float4 pv1 = p4[i0+256], tv1 = t4[i0+256];
        float pa[8] = {pv0.x,pv0.y,pv0.z,pv0.w, pv1.x,pv1.y,pv1.z,pv1.w};
        float ta[8] = {tv0.x,tv0.y,tv0.z,tv0.w, tv1.x,tv1.y,tv1.z,tv1.w};
#pragma unroll
        for (int j = 0; j < 8; ++j) {
            if (ta[j] > 0.f) {
                uint32_t kp = fkey(pa[j]), kt = fkey(ta[j]);
                if ((kp >> 10) == t22p) { atomicAdd(&cP[kp&1023u], 1u); atomicAdd(&sSP[kp&1023u], pa[j]); }
                else if ((kp >> 21) == b1p && (kp >> 10) < t22p) aP += pa[j];
                if ((kt >> 10) == t22t) { atomicAdd(&cT[kt&1023u], 1u); atomicAdd(&sST[kt&1023u], ta[j]); }
                else if ((kt >> 21) == b1t && (kt >> 10) < t22t) aT += ta[j];
            }
        }
    }
    const int lane = tid & 63, wv = tid >> 6;
    for (int off = 32; off; off >>= 1) { aP += __shfl_down(aP, off, 64); aT += __shfl_down(aT, off, 64); }
    if (lane == 0) { redP[wv] = aP; redT[wv] = aT; }
    __syncthreads();
    if (tid == 0) atomicAdd(&s2arr[b],        redP[0]+redP[1]+redP[2]+redP[3]);
    if (tid == 1) atomicAdd(&s2arr[NBATCH+b], redT[0]+redT[1]+redT[2]+redT[3]);
    for (int i = tid; i < BINS3; i += 256) {
        if (cP[i]) { atomicAdd(&cnt[(size_t)b*BINS3+i], cP[i]); atomicAdd(&sum3[(size_t)b*BINS3+i], sSP[i]); }
        if (cT[i]) { atomicAdd(&cnt[(size_t)(NBATCH+b)*BINS3+i], cT[i]); atomicAdd(&sum3[(size_t)(NBATCH+b)*BINS3+i], sST[i]); }
    }
    __threadfence();
    if (tid == 0) s_tick = atomicAdd(&done[b], 1u);
    __syncthreads();
    if (s_tick == HGX-1) {
        __threadfence();
        select_level<BINS3,2>(wu, wf, cnt, sum3, b);
        select_level<BINS3,2>(wu, wf, cnt, sum3, NBATCH+b);
    }
}

// ===== fused 4-scale gradient loss + residual sum; last block does the final combine =====
__global__ __launch_bounds__(256) void k_grad(const float* __restrict__ pred, const float* __restrict__ tgt,
                                              const float* __restrict__ shiftA, const float* __restrict__ sclA,
                                              float* __restrict__ gsum, uint32_t* __restrict__ gcnt,
                                              float* __restrict__ tsum,
                                              uint32_t* wu, uint32_t* doneg, float* __restrict__ out) {
    __shared__ float d_lds[GLH * GLW];
    const int b = blockIdx.y;
    const int bx = blockIdx.x & 3;       // 4 tiles across (4*128 = 512)
    const int by = blockIdx.x >> 2;      // 8 tiles down  (8*64  = 512)
    const int x0 = bx * GTW, y0 = by * GTH;
    const int tid = threadIdx.x;
    const float sp = shiftA[b], st = shiftA[NBATCH+b];
    const float ivp = 1.f/sclA[b], ivt = 1.f/sclA[NBATCH+b];
    const float NANF = __int_as_float(0x7FC00000);

    const float4* p4 = (const float4*)pred;
    const float4* t4 = (const float4*)tgt;
    const size_t base4 = (size_t)b * (NPIX/4);

    for (int i = tid; i < GLH * GL4; i += 256) {
        const int r = i / GL4, c4 = i - r * GL4;
        int yg = y0 + r;  if (yg > HH-1) yg = HH-1;
        int c4g = (x0 >> 2) + c4;
        if (c4g > (WW >> 2) - 1) c4g = (WW >> 2) - 1;
        const size_t gidx = base4 + (size_t)yg * (WW/4) + c4g;
        const float4 pv = p4[gidx], tv = t4[gidx];
        float dd[4];
        dd[0] = (tv.x > st) ? norm_diff(pv.x, tv.x, sp, ivp, st, ivt) : NANF;
        dd[1] = (tv.y > st) ? norm_diff(pv.y, tv.y, sp, ivp, st, ivt) : NANF;
        dd[2] = (tv.z > st) ? norm_diff(pv.z, tv.z, sp, ivp, st, ivt) : NANF;
        dd[3] = (tv.w > st) ? norm_diff(pv.w, tv.w, sp, ivp, st, ivt) : NANF;
        *(float4*)&d_lds[r * GLW + c4 * 4] = *(float4*)dd;
    }
    __syncthreads();

    const int xl = tid & (GTW - 1);
    const int yb = tid >> 7;
    const int xg = x0 + xl;
    float gs[4] = {0.f,0.f,0.f,0.f};
    uint32_t gc[4] = {0u,0u,0u,0u};
    float ts = 0.f;
#pragma unroll 4
    for (int k = 0; k < GTH/2; ++k) {
        const int yl = yb + 2*k;
        const int yg = y0 + yl;
        const float d0 = d_lds[yl * GLW + xl];
        const bool m0 = (d0 == d0);
        if (m0) ts += fabsf(d0);
#pragma unroll
        for (int sL = 0; sL < 4; ++sL) {
            const int s = 1 << sL;
            if ((xl & (s-1)) || (yl & (s-1))) continue;
            if (m0) gc[sL] += 1u;
            if (xg + s < WW) {
                const float v = fabsf(d_lds[yl * GLW + xl + s] - d0);
                if (v == v) gs[sL] += v;
            }
            if (yg + s < HH) {
                const float v = fabsf(d_lds[(yl + s) * GLW + xl] - d0);
                if (v == v) gs[sL] += v;
            }
        }
    }

    __shared__ float ls[4][4];
    __shared__ uint32_t lc[4][4];
    __shared__ float lt[4];
    __shared__ uint32_t s_tick;
    const int lane = tid & 63, wv = tid >> 6;
#pragma unroll
    for (int sL = 0; sL < 4; ++sL) {
        float v = gs[sL]; uint32_t cc = gc[sL];
        for (int off = 32; off; off >>= 1) { v += __shfl_down(v, off, 64); cc += __shfl_down(cc, off, 64); }
        if (lane == 0) { ls[sL][wv] = v; lc[sL][wv] = cc; }
    }
    for (int off = 32; off; off >>= 1) ts += __shfl_down(ts, off, 64);
    if (lane == 0) lt[wv] = ts;
    __syncthreads();
    if (tid < 4) {
        const int sL = tid;
        float v = ls[sL][0] + ls[sL][1] + ls[sL][2] + ls[sL][3];
        uint32_t cc = lc[sL][0] + lc[sL][1] + lc[sL][2] + lc[sL][3];
        if (v != 0.f) atomicAdd(&gsum[sL*NBATCH + b], v);
        if (cc)       atomicAdd(&gcnt[sL*NBATCH + b], cc);
    }
    if (tid == 4) {
        float v = lt[0] + lt[1] + lt[2] + lt[3];
        if (v != 0.f) atomicAdd(&tsum[b], v);
    }
    // ---- last block of the whole grid: final combine ----
    __threadfence();
    if (tid == 0) s_tick = atomicAdd(doneg, 1u);
    __syncthreads();
    if (s_tick == GGRID-1) {
        __threadfence();
        if (tid < 64) {
            const int bb = tid;
            uint32_t n2 = AGL_U(&wu[ST_N2 + NBATCH + bb]);
            float v = n2 ? AGL_F(&tsum[bb]) / (float)(2u*n2) : 0.f;
#pragma unroll
            for (int sL = 0; sL < 4; ++sL) {
                uint32_t cc = AGL_U(&gcnt[sL*NBATCH + bb]);
                float g = cc ? AGL_F(&gsum[sL*NBATCH + bb]) / (float)cc : 0.f;
                v += 0.5f * g;   // ALPHA = 0.5
            }
            for (int off = 32; off; off >>= 1) v += __shfl_down(v, off, 64);
            if (bb == 0) out[0] = v * (1.f/64.f);
        }
    }
}

extern "C" void kernel_launch(void* const* d_in, const int* in_sizes, int n_in,
                              void* d_out, int out_size, void* d_ws, size_t ws_size,
                              hipStream_t stream) {
    const float* pred = (const float*)d_in[0];
    const float* tgt  = (const float*)d_in[1];
    uint32_t* wu = (uint32_t*)d_ws;
    float*    wf = (float*)d_ws;
    if (ws_size < (size_t)WS_TOTAL * 4) return;  // ~3.2 MB needed

    hipMemsetAsync(d_ws, 0, (size_t)WS_TOTAL * 4, stream);
    dim3 hg(HGX, NBATCH);

    // --- medians + analytic MAD scale (3-level radix select, selects fused in-kernel) ---
    k_medhist1<<<hg, 256, 0, stream>>>(pred, tgt, wu + OFF_C1, wf + ST_STOT,
                                       wu, wf, wu + ST_DONE1);
    k_medhist2<<<hg, 256, 0, stream>>>(pred, tgt, wu + ST_B1, wu + OFF_C2, wf + ST_S1,
                                       wu, wf, wu + ST_DONE2);
    k_medhist3<<<hg, 256, 0, stream>>>(pred, tgt, wu + ST_B1, wu + ST_B2, wu + OFF_C3,
                                       wf + OFF_SUM3, wf + ST_S2,
                                       wu, wf, wu + ST_DONE3);

    // --- fused multiscale gradient loss + residual sum + final combine ---
    k_grad<<<dim3(32, NBATCH), 256, 0, stream>>>(pred, tgt, wf + ST_SHIFT, wf + ST_SCL,
                                                 wf + ST_GSUM, wu + ST_GCNT, wf + ST_TSUM,
                                                 wu, wu + ST_DONEG, (float*)d_out);
}

// Round 7
// 191.409 us; speedup vs baseline: 4.6168x; 4.6168x over previous
//
#include <hip/hip_runtime.h>
#include <stdint.h>

#define NBATCH 64
#define HH 512
#define WW 512
#define NPIX 262144            // 512*512
#define BINS1 2048             // key bits [31:21]
#define BINS2 2048             // key bits [20:10]
#define BINS3 1024             // key bits [9:0]
#define HGX 32                 // hist blocks per batch
#define HITER (NPIX/4/HGX/256) // float4 iters per hist block (= 8)

// ---------------- workspace layout (u32 units) ----------------
#define SZ_C1 (2*NBATCH*BINS1)
#define OFF_C1 0
#define OFF_C2 (OFF_C1 + SZ_C1)
#define SZ_C3 (2*NBATCH*BINS3)
#define OFF_C3 (OFF_C2 + SZ_C1)
#define OFF_SUM3 (OFF_C3 + SZ_C3)      // f32 [2*64][1024] level-3 bin sums
#define OFF_STATE (OFF_SUM3 + SZ_C3)
#define ST_N     (OFF_STATE)        // u32 [128] masked count per (tensor,batch)
#define ST_N2    (ST_N + 128)       // u32 [128] #{x > median}
#define ST_B1    (ST_N2 + 128)      // u32 [128]
#define ST_B2    (ST_B1 + 128)      // u32 [128]
#define ST_RANK  (ST_B2 + 128)      // u32 [128]
#define ST_CLT   (ST_RANK + 128)    // u32 [128] count strictly below bucket
#define ST_SHIFT (ST_CLT + 128)     // f32 [128] median
#define ST_SCL   (ST_SHIFT + 128)   // f32 [128] robust scale
#define ST_STOT  (ST_SCL + 128)     // f32 [128] sum of masked x
#define ST_S1    (ST_STOT + 128)    // f32 [128] sum of masked x, level-1 bucket < b1
#define ST_S2    (ST_S1 + 128)      // f32 [128] sum of masked x, bucket==b1, mid < b2
#define ST_TSUM  (ST_S2 + 128)      // f32 [64]  residual sum (trim provably no-op)
#define ST_GSUM  (ST_TSUM + 64)     // f32 [4*64] gradient sums
#define ST_GCNT  (ST_GSUM + 256)    // u32 [4*64] gradient mask counts
#define WS_TOTAL (ST_GCNT + 256)

// gradient tile geometry: 128x64 interior, 136x72 loaded (right/bottom halo 8)
// measured: 128x64 = 64.0 us vs 128x32 = 78.6 us (halo amplification beats occupancy)
#define GTW 128
#define GTH 64
#define GHALO 8
#define GLW (GTW + GHALO)      // 136
#define GLH (GTH + GHALO)      // 72
#define GL4 (GLW/4)            // 34

// order-preserving float -> u32 key
__device__ __forceinline__ uint32_t fkey(float x) {
    uint32_t u = __float_as_uint(x);
    return (u & 0x80000000u) ? ~u : (u | 0x80000000u);
}
__device__ __forceinline__ float funkey(uint32_t k) {
    return __uint_as_float((k & 0x80000000u) ? (k & 0x7fffffffu) : ~k);
}
__device__ __forceinline__ float norm_diff(float p, float t, float sp, float ivp, float st, float ivt) {
    return (p - sp)*ivp - (t - st)*ivt;
}

// ===== medhist1: level-1 counts (mask = tgt>0) + streaming S_tot for both tensors =====
__global__ __launch_bounds__(256) void k_medhist1(const float* __restrict__ pred, const float* __restrict__ tgt,
                                                  uint32_t* __restrict__ cnt, float* __restrict__ stot) {
    __shared__ uint32_t cP[BINS1], cT[BINS1];
    __shared__ float redP[4], redT[4];
    const int tid = threadIdx.x;
    for (int i = tid; i < BINS1; i += 256) { cP[i]=0u; cT[i]=0u; }
    __syncthreads();
    const int b = blockIdx.y;
    const float4* p4 = (const float4*)pred;
    const float4* t4 = (const float4*)tgt;
    size_t base = (size_t)b*(NPIX/4) + (size_t)blockIdx.x*(NPIX/4/HGX);
    float aP = 0.f, aT = 0.f;
    for (int it = 0; it < HITER; ++it) {
        size_t idx = base + (size_t)it*256 + tid;
        float4 pv = p4[idx], tv = t4[idx];
        float pa[4] = {pv.x, pv.y, pv.z, pv.w};
        float ta[4] = {tv.x, tv.y, tv.z, tv.w};
#pragma unroll
        for (int j = 0; j < 4; ++j) {
            if (ta[j] > 0.f) {
                atomicAdd(&cP[fkey(pa[j]) >> 21], 1u);
                atomicAdd(&cT[fkey(ta[j]) >> 21], 1u);
                aP += pa[j]; aT += ta[j];
            }
        }
    }
    const int lane = tid & 63, wv = tid >> 6;
    for (int off = 32; off; off >>= 1) { aP += __shfl_down(aP, off, 64); aT += __shfl_down(aT, off, 64); }
    if (lane == 0) { redP[wv] = aP; redT[wv] = aT; }
    __syncthreads();
    if (tid == 0) atomicAdd(&stot[b],        redP[0]+redP[1]+redP[2]+redP[3]);
    if (tid == 1) atomicAdd(&stot[NBATCH+b], redT[0]+redT[1]+redT[2]+redT[3]);
    for (int i = tid; i < BINS1; i += 256) {
        if (cP[i]) atomicAdd(&cnt[(size_t)b*BINS1+i], cP[i]);
        if (cT[i]) atomicAdd(&cnt[(size_t)(NBATCH+b)*BINS1+i], cT[i]);
    }
}

// ===== medhist2: level-2 counts + streaming S1 (sum of x in buckets < b1) =====
__global__ __launch_bounds__(256) void k_medhist2(const float* __restrict__ pred, const float* __restrict__ tgt,
                                                  const uint32_t* __restrict__ b1arr,
                                                  uint32_t* __restrict__ cnt, float* __restrict__ s1arr) {
    __shared__ uint32_t cP[BINS2], cT[BINS2];
    __shared__ float redP[4], redT[4];
    const int tid = threadIdx.x;
    for (int i = tid; i < BINS2; i += 256) { cP[i]=0u; cT[i]=0u; }
    __syncthreads();
    const int b = blockIdx.y;
    const uint32_t b1p = b1arr[b], b1t = b1arr[NBATCH+b];
    const float4* p4 = (const float4*)pred;
    const float4* t4 = (const float4*)tgt;
    size_t base = (size_t)b*(NPIX/4) + (size_t)blockIdx.x*(NPIX/4/HGX);
    float aP = 0.f, aT = 0.f;
    for (int it = 0; it < HITER; ++it) {
        size_t idx = base + (size_t)it*256 + tid;
        float4 pv = p4[idx], tv = t4[idx];
        float pa[4] = {pv.x, pv.y, pv.z, pv.w};
        float ta[4] = {tv.x, tv.y, tv.z, tv.w};
#pragma unroll
        for (int j = 0; j < 4; ++j) {
            if (ta[j] > 0.f) {
                uint32_t kp = fkey(pa[j]), kt = fkey(ta[j]);
                uint32_t hp = kp >> 21, ht = kt >> 21;
                if (hp == b1p) atomicAdd(&cP[(kp>>10)&2047u], 1u);
                else if (hp < b1p) aP += pa[j];
                if (ht == b1t) atomicAdd(&cT[(kt>>10)&2047u], 1u);
                else if (ht < b1t) aT += ta[j];
            }
        }
    }
    const int lane = tid & 63, wv = tid >> 6;
    for (int off = 32; off; off >>= 1) { aP += __shfl_down(aP, off, 64); aT += __shfl_down(aT, off, 64); }
    if (lane == 0) { redP[wv] = aP; redT[wv] = aT; }
    __syncthreads();
    if (tid == 0) atomicAdd(&s1arr[b],        redP[0]+redP[1]+redP[2]+redP[3]);
    if (tid == 1) atomicAdd(&s1arr[NBATCH+b], redT[0]+redT[1]+redT[2]+redT[3]);
    for (int i = tid; i < BINS2; i += 256) {
        if (cP[i]) atomicAdd(&cnt[(size_t)b*BINS2+i], cP[i]);
        if (cT[i]) atomicAdd(&cnt[(size_t)(NBATCH+b)*BINS2+i], cT[i]);
    }
}

// ===== medhist3: level-3 counts + SUMS (few elems -> cheap) + streaming S2 =====
__global__ __launch_bounds__(256) void k_medhist3(const float* __restrict__ pred, const float* __restrict__ tgt,
                                                  const uint32_t* __restrict__ b1arr, const uint32_t* __restrict__ b2arr,
                                                  uint32_t* __restrict__ cnt, float* __restrict__ sum3,
                                                  float* __restrict__ s2arr) {
    __shared__ uint32_t cP[BINS3], cT[BINS3];
    __shared__ float sSP[BINS3], sST[BINS3];
    __shared__ float redP[4], redT[4];
    const int tid = threadIdx.x;
    for (int i = tid; i < BINS3; i += 256) { cP[i]=0u; cT[i]=0u; sSP[i]=0.f; sST[i]=0.f; }
    __syncthreads();
    const int b = blockIdx.y;
    const uint32_t b1p = b1arr[b], b1t = b1arr[NBATCH+b];
    const uint32_t t22p = (b1p<<11) | b2arr[b];
    const uint32_t t22t = (b1t<<11) | b2arr[NBATCH+b];
    const float4* p4 = (const float4*)pred;
    const float4* t4 = (const float4*)tgt;
    size_t base = (size_t)b*(NPIX/4) + (size_t)blockIdx.x*(NPIX/4/HGX);
    float aP = 0.f, aT = 0.f;
    for (int it = 0; it < HITER; ++it) {
        size_t idx = base + (size_t)it*256 + tid;
        float4 pv = p4[idx], tv = t4[idx];
        float pa[4] = {pv.x, pv.y, pv.z, pv.w};
        float ta[4] = {tv.x, tv.y, tv.z, tv.w};
#pragma unroll
        for (int j = 0; j < 4; ++j) {
            if (ta[j] > 0.f) {
                uint32_t kp = fkey(pa[j]), kt = fkey(ta[j]);
                if ((kp >> 10) == t22p) { atomicAdd(&cP[kp&1023u], 1u); atomicAdd(&sSP[kp&1023u], pa[j]); }
                else if ((kp >> 21) == b1p && (kp >> 10) < t22p) aP += pa[j];
                if ((kt >> 10) == t22t) { atomicAdd(&cT[kt&1023u], 1u); atomicAdd(&sST[kt&1023u], ta[j]); }
                else if ((kt >> 21) == b1t && (kt >> 10) < t22t) aT += ta[j];
            }
        }
    }
    const int lane = tid & 63, wv = tid >> 6;
    for (int off = 32; off; off >>= 1) { aP += __shfl_down(aP, off, 64); aT += __shfl_down(aT, off, 64); }
    if (lane == 0) { redP[wv] = aP; redT[wv] = aT; }
    __syncthreads();
    if (tid == 0) atomicAdd(&s2arr[b],        redP[0]+redP[1]+redP[2]+redP[3]);
    if (tid == 1) atomicAdd(&s2arr[NBATCH+b], redT[0]+redT[1]+redT[2]+redT[3]);
    for (int i = tid; i < BINS3; i += 256) {
        if (cP[i]) { atomicAdd(&cnt[(size_t)b*BINS3+i], cP[i]); atomicAdd(&sum3[(size_t)b*BINS3+i], sSP[i]); }
        if (cT[i]) { atomicAdd(&cnt[(size_t)(NBATCH+b)*BINS3+i], cT[i]); atomicAdd(&sum3[(size_t)(NBATCH+b)*BINS3+i], sST[i]); }
    }
}

// ===== generic level select (median path only). At level 2 also computes MAD scale. =====
__global__ __launch_bounds__(256) void k_select(uint32_t* wu, float* wf,
                                                const uint32_t* cnt, const float* sum3,
                                                int nbins, int level) {
    const int q = blockIdx.x;       // 128 problems: tensor*64+batch
    const int tid = threadIdx.x;
    const int bpt = nbins >> 8;
    const uint32_t* c  = cnt  + (size_t)q*nbins + (size_t)tid*bpt;
    const float*    s3 = sum3 + (size_t)q*nbins + (size_t)tid*bpt;
    uint32_t tcnt = 0; float tfs = 0.f;
    for (int j = 0; j < bpt; ++j) tcnt += c[j];
    if (level == 2) for (int j = 0; j < bpt; ++j) tfs += s3[j];
    __shared__ uint32_t sc[256];
    __shared__ float ss[256];
    sc[tid] = tcnt; ss[tid] = tfs;
    __syncthreads();
    for (int off = 1; off < 256; off <<= 1) {
        uint32_t u = 0; float f = 0.f;
        if (tid >= off) { u = sc[tid-off]; f = ss[tid-off]; }
        __syncthreads();
        if (tid >= off) { sc[tid] += u; ss[tid] += f; }
        __syncthreads();
    }
    const uint32_t total = sc[255];
    const uint32_t excl = sc[tid] - tcnt;
    const float exclS = ss[tid] - tfs;

    uint32_t r;
    if (level == 0) {
        if (tid == 0) wu[ST_N+q] = total;
        r = total ? (total - 1u) / 2u : 0u;   // lower median rank
    } else {
        r = wu[ST_RANK+q];
    }
    __syncthreads();  // all threads read ST_RANK before the owner overwrites it

    if (total > 0u && excl <= r && r < excl + tcnt) {
        uint32_t cum = excl; float fs = exclS;
        for (int j = 0; j < bpt; ++j) {
            uint32_t cj = c[j];
            if (r < cum + cj) {
                uint32_t bidx = (uint32_t)(tid*bpt + j);
                if (level == 0) {
                    wu[ST_B1+q] = bidx; wu[ST_RANK+q] = r - cum; wu[ST_CLT+q] = cum;
                } else if (level == 1) {
                    wu[ST_B2+q] = bidx; wu[ST_RANK+q] = r - cum; wu[ST_CLT+q] += cum;
                } else {
                    uint32_t key = (wu[ST_B1+q] << 21) | (wu[ST_B2+q] << 10) | bidx;
                    float m = funkey(key);                     // exact lower median
                    uint32_t n = wu[ST_N+q];
                    uint32_t c_le = wu[ST_CLT+q] + cum + cj;   // #{x <= m} (all in bin b3 share key)
                    float S_le = wf[ST_S1+q] + wf[ST_S2+q] + fs + s3[j];
                    float madsum = (float)(2u*c_le - n) * m + wf[ST_STOT+q] - 2.f*S_le;
                    float scale = madsum / (float)(n ? n : 1u);
                    if (!(scale > 0.f)) scale = 1.f;           // ref: scale==0 -> 1
                    wf[ST_SHIFT+q] = m; wf[ST_SCL+q] = scale;
                    wu[ST_N2+q] = n - c_le;                    // #{x > median}
                }
                break;
            }
            cum += cj;
            if (level == 2) fs += s3[j];
        }
    }
    if (tid == 0 && total == 0u) {  // degenerate guard (no masked elements)
        if (level == 0)      { wu[ST_B1+q]=0; wu[ST_RANK+q]=0; wu[ST_CLT+q]=0; }
        else if (level == 1) { wu[ST_B2+q]=0; }
        else                 { wf[ST_SHIFT+q]=0.f; wf[ST_SCL+q]=1.f; wu[ST_N2+q]=0u; }
    }
}

// ===== fused 4-scale gradient loss + full residual sum (trim is a provable no-op) =====
// d staged in LDS; NaN marks unmasked (t <= median_t). 128x64 interior, 136x72 loaded.
__global__ __launch_bounds__(256) void k_grad(const float* __restrict__ pred, const float* __restrict__ tgt,
                                              const float* __restrict__ shiftA, const float* __restrict__ sclA,
                                              float* __restrict__ gsum, uint32_t* __restrict__ gcnt,
                                              float* __restrict__ tsum) {
    __shared__ float d_lds[GLH * GLW];
    const int b = blockIdx.y;
    const int bx = blockIdx.x & 3;       // 4 tiles across (4*128 = 512)
    const int by = blockIdx.x >> 2;      // 8 tiles down  (8*64  = 512)
    const int x0 = bx * GTW, y0 = by * GTH;
    const int tid = threadIdx.x;
    const float sp = shiftA[b], st = shiftA[NBATCH+b];
    const float ivp = 1.f/sclA[b], ivt = 1.f/sclA[NBATCH+b];
    const float NANF = __int_as_float(0x7FC00000);

    const float4* p4 = (const float4*)pred;
    const float4* t4 = (const float4*)tgt;
    const size_t base4 = (size_t)b * (NPIX/4);

    // ---- load 136x72 tile (clamped halo never read back), compute d, stage to LDS ----
    for (int i = tid; i < GLH * GL4; i += 256) {
        const int r = i / GL4, c4 = i - r * GL4;
        int yg = y0 + r;  if (yg > HH-1) yg = HH-1;
        int c4g = (x0 >> 2) + c4;
        if (c4g > (WW >> 2) - 1) c4g = (WW >> 2) - 1;
        const size_t gidx = base4 + (size_t)yg * (WW/4) + c4g;
        const float4 pv = p4[gidx], tv = t4[gidx];
        float dd[4];
        dd[0] = (tv.x > st) ? norm_diff(pv.x, tv.x, sp, ivp, st, ivt) : NANF;
        dd[1] = (tv.y > st) ? norm_diff(pv.y, tv.y, sp, ivp, st, ivt) : NANF;
        dd[2] = (tv.z > st) ? norm_diff(pv.z, tv.z, sp, ivp, st, ivt) : NANF;
        dd[3] = (tv.w > st) ? norm_diff(pv.w, tv.w, sp, ivp, st, ivt) : NANF;
        *(float4*)&d_lds[r * GLW + c4 * 4] = *(float4*)dd;
    }
    __syncthreads();

    // ---- compute: thread owns column xl = tid%128, rows yb, yb+2, ... (32 px) ----
    const int xl = tid & (GTW - 1);
    const int yb = tid >> 7;             // 0 or 1
    const int xg = x0 + xl;
    float gs[4] = {0.f,0.f,0.f,0.f};
    uint32_t gc[4] = {0u,0u,0u,0u};
    float ts = 0.f;
#pragma unroll 4
    for (int k = 0; k < GTH/2; ++k) {
        const int yl = yb + 2*k;
        const int yg = y0 + yl;
        const float d0 = d_lds[yl * GLW + xl];
        const bool m0 = (d0 == d0);
        if (m0) ts += fabsf(d0);         // trimmed sum == full sum (thr always clamps to max)
#pragma unroll
        for (int sL = 0; sL < 4; ++sL) {
            const int s = 1 << sL;
            if ((xl & (s-1)) || (yl & (s-1))) continue;
            if (m0) gc[sL] += 1u;
            if (xg + s < WW) {
                const float v = fabsf(d_lds[yl * GLW + xl + s] - d0);
                if (v == v) gs[sL] += v;
            }
            if (yg + s < HH) {
                const float v = fabsf(d_lds[(yl + s) * GLW + xl] - d0);
                if (v == v) gs[sL] += v;
            }
        }
    }

    // ---- block reduce + global atomics ----
    __shared__ float ls[4][4];
    __shared__ uint32_t lc[4][4];
    __shared__ float lt[4];
    const int lane = tid & 63, wv = tid >> 6;
#pragma unroll
    for (int sL = 0; sL < 4; ++sL) {
        float v = gs[sL]; uint32_t cc = gc[sL];
        for (int off = 32; off; off >>= 1) { v += __shfl_down(v, off, 64); cc += __shfl_down(cc, off, 64); }
        if (lane == 0) { ls[sL][wv] = v; lc[sL][wv] = cc; }
    }
    for (int off = 32; off; off >>= 1) ts += __shfl_down(ts, off, 64);
    if (lane == 0) lt[wv] = ts;
    __syncthreads();
    if (tid < 4) {
        const int sL = tid;
        float v = ls[sL][0] + ls[sL][1] + ls[sL][2] + ls[sL][3];
        uint32_t cc = lc[sL][0] + lc[sL][1] + lc[sL][2] + lc[sL][3];
        if (v != 0.f) atomicAdd(&gsum[sL*NBATCH + b], v);
        if (cc)       atomicAdd(&gcnt[sL*NBATCH + b], cc);
    }
    if (tid == 4) {
        float v = lt[0] + lt[1] + lt[2] + lt[3];
        if (v != 0.f) atomicAdd(&tsum[b], v);
    }
}

// ================= final combine =================
__global__ void k_final(const uint32_t* __restrict__ wu, const float* __restrict__ tsum,
                        const float* __restrict__ gsum, const uint32_t* __restrict__ gcnt,
                        float* __restrict__ out) {
    const int b = threadIdx.x;  // 64 threads, one wave
    uint32_t n2 = wu[ST_N2 + NBATCH + b];
    float v = n2 ? tsum[b] / (float)(2u*n2) : 0.f;
#pragma unroll
    for (int sL = 0; sL < 4; ++sL) {
        uint32_t cc = gcnt[sL*NBATCH + b];
        float g = cc ? gsum[sL*NBATCH + b] / (float)cc : 0.f;
        v += 0.5f * g;   // ALPHA = 0.5
    }
    for (int off = 32; off; off >>= 1) v += __shfl_down(v, off, 64);
    if (b == 0) out[0] = v * (1.f/64.f);
}

extern "C" void kernel_launch(void* const* d_in, const int* in_sizes, int n_in,
                              void* d_out, int out_size, void* d_ws, size_t ws_size,
                              hipStream_t stream) {
    const float* pred = (const float*)d_in[0];
    const float* tgt  = (const float*)d_in[1];
    uint32_t* wu = (uint32_t*)d_ws;
    float*    wf = (float*)d_ws;
    if (ws_size < (size_t)WS_TOTAL * 4) return;  // ~3.2 MB needed

    hipMemsetAsync(d_ws, 0, (size_t)WS_TOTAL * 4, stream);
    dim3 hg(HGX, NBATCH);

    // --- medians + analytic MAD scale (3-level radix select, sum-augmented level 3) ---
    k_medhist1<<<hg, 256, 0, stream>>>(pred, tgt, wu + OFF_C1, wf + ST_STOT);
    k_select<<<128, 256, 0, stream>>>(wu, wf, wu + OFF_C1, wf + OFF_SUM3, BINS1, 0);
    k_medhist2<<<hg, 256, 0, stream>>>(pred, tgt, wu + ST_B1, wu + OFF_C2, wf + ST_S1);
    k_select<<<128, 256, 0, stream>>>(wu, wf, wu + OFF_C2, wf + OFF_SUM3, BINS2, 1);
    k_medhist3<<<hg, 256, 0, stream>>>(pred, tgt, wu + ST_B1, wu + ST_B2, wu + OFF_C3,
                                       wf + OFF_SUM3, wf + ST_S2);
    k_select<<<128, 256, 0, stream>>>(wu, wf, wu + OFF_C3, wf + OFF_SUM3, BINS3, 2);

    // --- fused multiscale gradient loss + residual sum (tiled) ---
    k_grad<<<dim3(32, NBATCH), 256, 0, stream>>>(pred, tgt, wf + ST_SHIFT, wf + ST_SCL,
                                                 wf + ST_GSUM, wu + ST_GCNT, wf + ST_TSUM);
    // --- combine ---
    k_final<<<1, 64, 0, stream>>>(wu, wf + ST_TSUM, wf + ST_GSUM, wu + ST_GCNT, (float*)d_out);
}

// Round 8
// 173.951 us; speedup vs baseline: 5.0802x; 1.1004x over previous
//
#include <hip/hip_runtime.h>
#include <stdint.h>

#define NBATCH 64
#define HH 512
#define WW 512
#define NPIX 262144            // 512*512
#define BINS1 2048             // key bits [31:21]
#define BINS2 2048             // key bits [20:10]
#define BINS3 1024             // key bits [9:0]
#define HGX 32                 // hist blocks per batch
#define HITER (NPIX/4/HGX/256) // float4 iters per hist block (= 8)

// ---------------- workspace layout (u32 units) ----------------
#define SZ_C1 (2*NBATCH*BINS1)
#define OFF_C1 0
#define OFF_C2 (OFF_C1 + SZ_C1)
#define SZ_C3 (2*NBATCH*BINS3)
#define OFF_C3 (OFF_C2 + SZ_C1)
#define OFF_SUM3 (OFF_C3 + SZ_C3)      // f32 [2*64][1024] level-3 bin sums
#define OFF_STATE (OFF_SUM3 + SZ_C3)
#define ST_N     (OFF_STATE)        // u32 [128] masked count per (tensor,batch)
#define ST_N2    (ST_N + 128)       // u32 [128] #{x > median}
#define ST_B1    (ST_N2 + 128)      // u32 [128]
#define ST_B2    (ST_B1 + 128)      // u32 [128]
#define ST_RANK  (ST_B2 + 128)      // u32 [128]
#define ST_CLT   (ST_RANK + 128)    // u32 [128] count strictly below bucket
#define ST_SHIFT (ST_CLT + 128)     // f32 [128] median
#define ST_SCL   (ST_SHIFT + 128)   // f32 [128] robust scale
#define ST_STOT  (ST_SCL + 128)     // f32 [128] sum of masked x
#define ST_S1    (ST_STOT + 128)    // f32 [128] sum of masked x, level-1 bucket < b1
#define ST_S2    (ST_S1 + 128)      // f32 [128] sum of masked x, bucket==b1, mid < b2
#define ST_TSUM  (ST_S2 + 128)      // f32 [64]  residual sum (trim provably no-op)
#define ST_GSUM  (ST_TSUM + 64)     // f32 [4*64] gradient sums
#define ST_GCNT  (ST_GSUM + 256)    // u32 [4*64] gradient mask counts
#define WS_TOTAL (ST_GCNT + 256)

// gradient tile geometry: 128x64 interior, 136x72 loaded (right/bottom halo 8)
#define GTW 128
#define GTH 64
#define GHALO 8
#define GLW (GTW + GHALO)      // 136
#define GLH (GTH + GHALO)      // 72
#define GL4 (GLW/4)            // 34

// order-preserving float -> u32 key
__device__ __forceinline__ uint32_t fkey(float x) {
    uint32_t u = __float_as_uint(x);
    return (u & 0x80000000u) ? ~u : (u | 0x80000000u);
}
__device__ __forceinline__ float funkey(uint32_t k) {
    return __uint_as_float((k & 0x80000000u) ? (k & 0x7fffffffu) : ~k);
}
__device__ __forceinline__ float norm_diff(float p, float t, float sp, float ivp, float st, float ivt) {
    return (p - sp)*ivp - (t - st)*ivt;
}

// ===== medhist1: level-1 counts (mask = tgt>0) + streaming S_tot for both tensors =====
__global__ __launch_bounds__(256) void k_medhist1(const float* __restrict__ pred, const float* __restrict__ tgt,
                                                  uint32_t* __restrict__ cnt, float* __restrict__ stot) {
    __shared__ uint32_t cP[BINS1], cT[BINS1];
    __shared__ float redP[4], redT[4];
    const int tid = threadIdx.x;
    for (int i = tid; i < BINS1; i += 256) { cP[i]=0u; cT[i]=0u; }
    __syncthreads();
    const int b = blockIdx.y;
    const float4* p4 = (const float4*)pred;
    const float4* t4 = (const float4*)tgt;
    size_t base = (size_t)b*(NPIX/4) + (size_t)blockIdx.x*(NPIX/4/HGX);
    float aP = 0.f, aT = 0.f;
    for (int it = 0; it < HITER; it += 2) {   // unroll 2: 4 independent 16B loads in flight
        size_t i0 = base + (size_t)it*256 + tid;
        float4 pv0 = p4[i0], tv0 = t4[i0];
        float4 pv1 = p4[i0+256], tv1 = t4[i0+256];
        float pa[8] = {pv0.x,pv0.y,pv0.z,pv0.w, pv1.x,pv1.y,pv1.z,pv1.w};
        float ta[8] = {tv0.x,tv0.y,tv0.z,tv0.w, tv1.x,tv1.y,tv1.z,tv1.w};
#pragma unroll
        for (int j = 0; j < 8; ++j) {
            if (ta[j] > 0.f) {
                atomicAdd(&cP[fkey(pa[j]) >> 21], 1u);
                atomicAdd(&cT[fkey(ta[j]) >> 21], 1u);
                aP += pa[j]; aT += ta[j];
            }
        }
    }
    const int lane = tid & 63, wv = tid >> 6;
    for (int off = 32; off; off >>= 1) { aP += __shfl_down(aP, off, 64); aT += __shfl_down(aT, off, 64); }
    if (lane == 0) { redP[wv] = aP; redT[wv] = aT; }
    __syncthreads();
    if (tid == 0) atomicAdd(&stot[b],        redP[0]+redP[1]+redP[2]+redP[3]);
    if (tid == 1) atomicAdd(&stot[NBATCH+b], redT[0]+redT[1]+redT[2]+redT[3]);
    for (int i = tid; i < BINS1; i += 256) {
        if (cP[i]) atomicAdd(&cnt[(size_t)b*BINS1+i], cP[i]);
        if (cT[i]) atomicAdd(&cnt[(size_t)(NBATCH+b)*BINS1+i], cT[i]);
    }
}

// ===== medhist2: level-2 counts + streaming S1 (sum of x in buckets < b1) =====
__global__ __launch_bounds__(256) void k_medhist2(const float* __restrict__ pred, const float* __restrict__ tgt,
                                                  const uint32_t* __restrict__ b1arr,
                                                  uint32_t* __restrict__ cnt, float* __restrict__ s1arr) {
    __shared__ uint32_t cP[BINS2], cT[BINS2];
    __shared__ float redP[4], redT[4];
    const int tid = threadIdx.x;
    for (int i = tid; i < BINS2; i += 256) { cP[i]=0u; cT[i]=0u; }
    __syncthreads();
    const int b = blockIdx.y;
    const uint32_t b1p = b1arr[b], b1t = b1arr[NBATCH+b];
    const float4* p4 = (const float4*)pred;
    const float4* t4 = (const float4*)tgt;
    size_t base = (size_t)b*(NPIX/4) + (size_t)blockIdx.x*(NPIX/4/HGX);
    float aP = 0.f, aT = 0.f;
    for (int it = 0; it < HITER; it += 2) {
        size_t i0 = base + (size_t)it*256 + tid;
        float4 pv0 = p4[i0], tv0 = t4[i0];
        float4 pv1 = p4[i0+256], tv1 = t4[i0+256];
        float pa[8] = {pv0.x,pv0.y,pv0.z,pv0.w, pv1.x,pv1.y,pv1.z,pv1.w};
        float ta[8] = {tv0.x,tv0.y,tv0.z,tv0.w, tv1.x,tv1.y,tv1.z,tv1.w};
#pragma unroll
        for (int j = 0; j < 8; ++j) {
            if (ta[j] > 0.f) {
                uint32_t kp = fkey(pa[j]), kt = fkey(ta[j]);
                uint32_t hp = kp >> 21, ht = kt >> 21;
                if (hp == b1p) atomicAdd(&cP[(kp>>10)&2047u], 1u);
                else if (hp < b1p) aP += pa[j];
                if (ht == b1t) atomicAdd(&cT[(kt>>10)&2047u], 1u);
                else if (ht < b1t) aT += ta[j];
            }
        }
    }
    const int lane = tid & 63, wv = tid >> 6;
    for (int off = 32; off; off >>= 1) { aP += __shfl_down(aP, off, 64); aT += __shfl_down(aT, off, 64); }
    if (lane == 0) { redP[wv] = aP; redT[wv] = aT; }
    __syncthreads();
    if (tid == 0) atomicAdd(&s1arr[b],        redP[0]+redP[1]+redP[2]+redP[3]);
    if (tid == 1) atomicAdd(&s1arr[NBATCH+b], redT[0]+redT[1]+redT[2]+redT[3]);
    for (int i = tid; i < BINS2; i += 256) {
        if (cP[i]) atomicAdd(&cnt[(size_t)b*BINS2+i], cP[i]);
        if (cT[i]) atomicAdd(&cnt[(size_t)(NBATCH+b)*BINS2+i], cT[i]);
    }
}

// ===== medhist3: level-3 counts + SUMS (few elems -> cheap) + streaming S2 =====
__global__ __launch_bounds__(256) void k_medhist3(const float* __restrict__ pred, const float* __restrict__ tgt,
                                                  const uint32_t* __restrict__ b1arr, const uint32_t* __restrict__ b2arr,
                                                  uint32_t* __restrict__ cnt, float* __restrict__ sum3,
                                                  float* __restrict__ s2arr) {
    __shared__ uint32_t cP[BINS3], cT[BINS3];
    __shared__ float sSP[BINS3], sST[BINS3];
    __shared__ float redP[4], redT[4];
    const int tid = threadIdx.x;
    for (int i = tid; i < BINS3; i += 256) { cP[i]=0u; cT[i]=0u; sSP[i]=0.f; sST[i]=0.f; }
    __syncthreads();
    const int b = blockIdx.y;
    const uint32_t b1p = b1arr[b], b1t = b1arr[NBATCH+b];
    const uint32_t t22p = (b1p<<11) | b2arr[b];
    const uint32_t t22t = (b1t<<11) | b2arr[NBATCH+b];
    const float4* p4 = (const float4*)pred;
    const float4* t4 = (const float4*)tgt;
    size_t base = (size_t)b*(NPIX/4) + (size_t)blockIdx.x*(NPIX/4/HGX);
    float aP = 0.f, aT = 0.f;
    for (int it = 0; it < HITER; it += 2) {
        size_t i0 = base + (size_t)it*256 + tid;
        float4 pv0 = p4[i0], tv0 = t4[i0];
        float4 pv1 = p4[i0+256], tv1 = t4[i0+256];
        float pa[8] = {pv0.x,pv0.y,pv0.z,pv0.w, pv1.x,pv1.y,pv1.z,pv1.w};
        float ta[8] = {tv0.x,tv0.y,tv0.z,tv0.w, tv1.x,tv1.y,tv1.z,tv1.w};
#pragma unroll
        for (int j = 0; j < 8; ++j) {
            if (ta[j] > 0.f) {
                uint32_t kp = fkey(pa[j]), kt = fkey(ta[j]);
                if ((kp >> 10) == t22p) { atomicAdd(&cP[kp&1023u], 1u); atomicAdd(&sSP[kp&1023u], pa[j]); }
                else if ((kp >> 21) == b1p && (kp >> 10) < t22p) aP += pa[j];
                if ((kt >> 10) == t22t) { atomicAdd(&cT[kt&1023u], 1u); atomicAdd(&sST[kt&1023u], ta[j]); }
                else if ((kt >> 21) == b1t && (kt >> 10) < t22t) aT += ta[j];
            }
        }
    }
    const int lane = tid & 63, wv = tid >> 6;
    for (int off = 32; off; off >>= 1) { aP += __shfl_down(aP, off, 64); aT += __shfl_down(aT, off, 64); }
    if (lane == 0) { redP[wv] = aP; redT[wv] = aT; }
    __syncthreads();
    if (tid == 0) atomicAdd(&s2arr[b],        redP[0]+redP[1]+redP[2]+redP[3]);
    if (tid == 1) atomicAdd(&s2arr[NBATCH+b], redT[0]+redT[1]+redT[2]+redT[3]);
    for (int i = tid; i < BINS3; i += 256) {
        if (cP[i]) { atomicAdd(&cnt[(size_t)b*BINS3+i], cP[i]); atomicAdd(&sum3[(size_t)b*BINS3+i], sSP[i]); }
        if (cT[i]) { atomicAdd(&cnt[(size_t)(NBATCH+b)*BINS3+i], cT[i]); atomicAdd(&sum3[(size_t)(NBATCH+b)*BINS3+i], sST[i]); }
    }
}

// ===== generic level select (median path only). At level 2 also computes MAD scale. =====
__global__ __launch_bounds__(256) void k_select(uint32_t* wu, float* wf,
                                                const uint32_t* cnt, const float* sum3,
                                                int nbins, int level) {
    const int q = blockIdx.x;       // 128 problems: tensor*64+batch
    const int tid = threadIdx.x;
    const int bpt = nbins >> 8;
    const uint32_t* c  = cnt  + (size_t)q*nbins + (size_t)tid*bpt;
    const float*    s3 = sum3 + (size_t)q*nbins + (size_t)tid*bpt;
    uint32_t tcnt = 0; float tfs = 0.f;
    for (int j = 0; j < bpt; ++j) tcnt += c[j];
    if (level == 2) for (int j = 0; j < bpt; ++j) tfs += s3[j];
    __shared__ uint32_t sc[256];
    __shared__ float ss[256];
    sc[tid] = tcnt; ss[tid] = tfs;
    __syncthreads();
    for (int off = 1; off < 256; off <<= 1) {
        uint32_t u = 0; float f = 0.f;
        if (tid >= off) { u = sc[tid-off]; f = ss[tid-off]; }
        __syncthreads();
        if (tid >= off) { sc[tid] += u; ss[tid] += f; }
        __syncthreads();
    }
    const uint32_t total = sc[255];
    const uint32_t excl = sc[tid] - tcnt;
    const float exclS = ss[tid] - tfs;

    uint32_t r;
    if (level == 0) {
        if (tid == 0) wu[ST_N+q] = total;
        r = total ? (total - 1u) / 2u : 0u;   // lower median rank
    } else {
        r = wu[ST_RANK+q];
    }
    __syncthreads();  // all threads read ST_RANK before the owner overwrites it

    if (total > 0u && excl <= r && r < excl + tcnt) {
        uint32_t cum = excl; float fs = exclS;
        for (int j = 0; j < bpt; ++j) {
            uint32_t cj = c[j];
            if (r < cum + cj) {
                uint32_t bidx = (uint32_t)(tid*bpt + j);
                if (level == 0) {
                    wu[ST_B1+q] = bidx; wu[ST_RANK+q] = r - cum; wu[ST_CLT+q] = cum;
                } else if (level == 1) {
                    wu[ST_B2+q] = bidx; wu[ST_RANK+q] = r - cum; wu[ST_CLT+q] += cum;
                } else {
                    uint32_t key = (wu[ST_B1+q] << 21) | (wu[ST_B2+q] << 10) | bidx;
                    float m = funkey(key);                     // exact lower median
                    uint32_t n = wu[ST_N+q];
                    uint32_t c_le = wu[ST_CLT+q] + cum + cj;   // #{x <= m}
                    float S_le = wf[ST_S1+q] + wf[ST_S2+q] + fs + s3[j];
                    float madsum = (float)(2u*c_le - n) * m + wf[ST_STOT+q] - 2.f*S_le;
                    float scale = madsum / (float)(n ? n : 1u);
                    if (!(scale > 0.f)) scale = 1.f;           // ref: scale==0 -> 1
                    wf[ST_SHIFT+q] = m; wf[ST_SCL+q] = scale;
                    wu[ST_N2+q] = n - c_le;                    // #{x > median}
                }
                break;
            }
            cum += cj;
            if (level == 2) fs += s3[j];
        }
    }
    if (tid == 0 && total == 0u) {  // degenerate guard (no masked elements)
        if (level == 0)      { wu[ST_B1+q]=0; wu[ST_RANK+q]=0; wu[ST_CLT+q]=0; }
        else if (level == 1) { wu[ST_B2+q]=0; }
        else                 { wf[ST_SHIFT+q]=0.f; wf[ST_SCL+q]=1.f; wu[ST_N2+q]=0u; }
    }
}

// ===== fused 4-scale gradient loss + residual sum — DENSE per-scale loops =====
// d staged in LDS; NaN marks unmasked (t <= median_t). 128x64 interior, 136x72 loaded.
// Scales processed in separate dense loops (no exec-masked dead lanes).
__global__ __launch_bounds__(256) void k_grad(const float* __restrict__ pred, const float* __restrict__ tgt,
                                              const float* __restrict__ shiftA, const float* __restrict__ sclA,
                                              float* __restrict__ gsum, uint32_t* __restrict__ gcnt,
                                              float* __restrict__ tsum) {
    __shared__ float d_lds[GLH * GLW];
    const int b = blockIdx.y;
    const int bx = blockIdx.x & 3;       // 4 tiles across
    const int by = blockIdx.x >> 2;      // 8 tiles down
    const int x0 = bx * GTW, y0 = by * GTH;
    const int tid = threadIdx.x;
    const float sp = shiftA[b], st = shiftA[NBATCH+b];
    const float ivp = 1.f/sclA[b], ivt = 1.f/sclA[NBATCH+b];
    const float NANF = __int_as_float(0x7FC00000);

    const float4* p4 = (const float4*)pred;
    const float4* t4 = (const float4*)tgt;
    const size_t base4 = (size_t)b * (NPIX/4);

    // ---- load 136x72 tile (clamped halo never read back), compute d, stage to LDS ----
    for (int i = tid; i < GLH * GL4; i += 256) {
        const int r = i / GL4, c4 = i - r * GL4;
        int yg = y0 + r;  if (yg > HH-1) yg = HH-1;
        int c4g = (x0 >> 2) + c4;
        if (c4g > (WW >> 2) - 1) c4g = (WW >> 2) - 1;
        const size_t gidx = base4 + (size_t)yg * (WW/4) + c4g;
        const float4 pv = p4[gidx], tv = t4[gidx];
        float dd[4];
        dd[0] = (tv.x > st) ? norm_diff(pv.x, tv.x, sp, ivp, st, ivt) : NANF;
        dd[1] = (tv.y > st) ? norm_diff(pv.y, tv.y, sp, ivp, st, ivt) : NANF;
        dd[2] = (tv.z > st) ? norm_diff(pv.z, tv.z, sp, ivp, st, ivt) : NANF;
        dd[3] = (tv.w > st) ? norm_diff(pv.w, tv.w, sp, ivp, st, ivt) : NANF;
        *(float4*)&d_lds[r * GLW + c4 * 4] = *(float4*)dd;
    }
    __syncthreads();

    float gs[4] = {0.f,0.f,0.f,0.f};
    uint32_t gc[4] = {0u,0u,0u,0u};
    float ts = 0.f;

    // ---- scale 0 (s=1): dense, 32 px/thread + trim sum ----
    {
        const int xl = tid & (GTW - 1);
        const int yb = tid >> 7;
        const int xg = x0 + xl;
#pragma unroll 4
        for (int k = 0; k < GTH/2; ++k) {
            const int yl = yb + 2*k;
            const int yg = y0 + yl;
            const float d0 = d_lds[yl * GLW + xl];
            const bool m0 = (d0 == d0);
            if (m0) { ts += fabsf(d0); gc[0] += 1u; }
            if (xg + 1 < WW) {
                const float v = fabsf(d_lds[yl * GLW + xl + 1] - d0);
                if (v == v) gs[0] += v;
            }
            if (yg + 1 < HH) {
                const float v = fabsf(d_lds[(yl + 1) * GLW + xl] - d0);
                if (v == v) gs[0] += v;
            }
        }
    }
    // ---- scale 1 (s=2): 64x32 = 2048 active px, 8/thread ----
#pragma unroll
    for (int j = 0; j < 8; ++j) {
        const int i = tid + 256*j;
        const int xl = (i & 63) << 1, yl = (i >> 6) << 1;
        const int xg = x0 + xl, yg = y0 + yl;
        const float d0 = d_lds[yl * GLW + xl];
        if (d0 == d0) gc[1] += 1u;
        if (xg + 2 < WW) {
            const float v = fabsf(d_lds[yl * GLW + xl + 2] - d0);
            if (v == v) gs[1] += v;
        }
        if (yg + 2 < HH) {
            const float v = fabsf(d_lds[(yl + 2) * GLW + xl] - d0);
            if (v == v) gs[1] += v;
        }
    }
    // ---- scale 2 (s=4): 32x16 = 512 active px, 2/thread ----
#pragma unroll
    for (int j = 0; j < 2; ++j) {
        const int i = tid + 256*j;
        const int xl = (i & 31) << 2, yl = (i >> 5) << 2;
        const int xg = x0 + xl, yg = y0 + yl;
        const float d0 = d_lds[yl * GLW + xl];
        if (d0 == d0) gc[2] += 1u;
        if (xg + 4 < WW) {
            const float v = fabsf(d_lds[yl * GLW + xl + 4] - d0);
            if (v == v) gs[2] += v;
        }
        if (yg + 4 < HH) {
            const float v = fabsf(d_lds[(yl + 4) * GLW + xl] - d0);
            if (v == v) gs[2] += v;
        }
    }
    // ---- scale 3 (s=8): 16x8 = 128 active px, threads < 128 ----
    if (tid < 128) {
        const int xl = (tid & 15) << 3, yl = (tid >> 4) << 3;
        const int xg = x0 + xl, yg = y0 + yl;
        const float d0 = d_lds[yl * GLW + xl];
        if (d0 == d0) gc[3] += 1u;
        if (xg + 8 < WW) {
            const float v = fabsf(d_lds[yl * GLW + xl + 8] - d0);
            if (v == v) gs[3] += v;
        }
        if (yg + 8 < HH) {
            const float v = fabsf(d_lds[(yl + 8) * GLW + xl] - d0);
            if (v == v) gs[3] += v;
        }
    }

    // ---- block reduce + global atomics ----
    __shared__ float ls[4][4];
    __shared__ uint32_t lc[4][4];
    __shared__ float lt[4];
    const int lane = tid & 63, wv = tid >> 6;
#pragma unroll
    for (int sL = 0; sL < 4; ++sL) {
        float v = gs[sL]; uint32_t cc = gc[sL];
        for (int off = 32; off; off >>= 1) { v += __shfl_down(v, off, 64); cc += __shfl_down(cc, off, 64); }
        if (lane == 0) { ls[sL][wv] = v; lc[sL][wv] = cc; }
    }
    for (int off = 32; off; off >>= 1) ts += __shfl_down(ts, off, 64);
    if (lane == 0) lt[wv] = ts;
    __syncthreads();
    if (tid < 4) {
        const int sL = tid;
        float v = ls[sL][0] + ls[sL][1] + ls[sL][2] + ls[sL][3];
        uint32_t cc = lc[sL][0] + lc[sL][1] + lc[sL][2] + lc[sL][3];
        if (v != 0.f) atomicAdd(&gsum[sL*NBATCH + b], v);
        if (cc)       atomicAdd(&gcnt[sL*NBATCH + b], cc);
    }
    if (tid == 4) {
        float v = lt[0] + lt[1] + lt[2] + lt[3];
        if (v != 0.f) atomicAdd(&tsum[b], v);
    }
}

// ================= final combine =================
__global__ void k_final(const uint32_t* __restrict__ wu, const float* __restrict__ tsum,
                        const float* __restrict__ gsum, const uint32_t* __restrict__ gcnt,
                        float* __restrict__ out) {
    const int b = threadIdx.x;  // 64 threads, one wave
    uint32_t n2 = wu[ST_N2 + NBATCH + b];
    float v = n2 ? tsum[b] / (float)(2u*n2) : 0.f;
#pragma unroll
    for (int sL = 0; sL < 4; ++sL) {
        uint32_t cc = gcnt[sL*NBATCH + b];
        float g = cc ? gsum[sL*NBATCH + b] / (float)cc : 0.f;
        v += 0.5f * g;   // ALPHA = 0.5
    }
    for (int off = 32; off; off >>= 1) v += __shfl_down(v, off, 64);
    if (b == 0) out[0] = v * (1.f/64.f);
}

extern "C" void kernel_launch(void* const* d_in, const int* in_sizes, int n_in,
                              void* d_out, int out_size, void* d_ws, size_t ws_size,
                              hipStream_t stream) {
    const float* pred = (const float*)d_in[0];
    const float* tgt  = (const float*)d_in[1];
    uint32_t* wu = (uint32_t*)d_ws;
    float*    wf = (float*)d_ws;
    if (ws_size < (size_t)WS_TOTAL * 4) return;  // ~3.2 MB needed

    hipMemsetAsync(d_ws, 0, (size_t)WS_TOTAL * 4, stream);
    dim3 hg(HGX, NBATCH);

    // --- medians + analytic MAD scale (3-level radix select, sum-augmented level 3) ---
    k_medhist1<<<hg, 256, 0, stream>>>(pred, tgt, wu + OFF_C1, wf + ST_STOT);
    k_select<<<128, 256, 0, stream>>>(wu, wf, wu + OFF_C1, wf + OFF_SUM3, BINS1, 0);
    k_medhist2<<<hg, 256, 0, stream>>>(pred, tgt, wu + ST_B1, wu + OFF_C2, wf + ST_S1);
    k_select<<<128, 256, 0, stream>>>(wu, wf, wu + OFF_C2, wf + OFF_SUM3, BINS2, 1);
    k_medhist3<<<hg, 256, 0, stream>>>(pred, tgt, wu + ST_B1, wu + ST_B2, wu + OFF_C3,
                                       wf + OFF_SUM3, wf + ST_S2);
    k_select<<<128, 256, 0, stream>>>(wu, wf, wu + OFF_C3, wf + OFF_SUM3, BINS3, 2);

    // --- fused multiscale gradient loss + residual sum (tiled, dense per-scale) ---
    k_grad<<<dim3(32, NBATCH), 256, 0, stream>>>(pred, tgt, wf + ST_SHIFT, wf + ST_SCL,
                                                 wf + ST_GSUM, wu + ST_GCNT, wf + ST_TSUM);
    // --- combine ---
    k_final<<<1, 64, 0, stream>>>(wu, wf + ST_TSUM, wf + ST_GSUM, wu + ST_GCNT, (float*)d_out);
}

// Round 9
// 169.872 us; speedup vs baseline: 5.2021x; 1.0240x over previous
//
#include <hip/hip_runtime.h>
#include <stdint.h>

#define NBATCH 64
#define HH 512
#define WW 512
#define NPIX 262144            // 512*512
#define BINS1 2048             // key bits [31:21]
#define BINS2 2048             // key bits [20:10]
#define BINS3 1024             // key bits [9:0]
#define HGX 32                 // hist blocks per batch
#define HITER (NPIX/4/HGX/256) // float4 iters per hist block (= 8)

// ---------------- workspace layout (u32 units) ----------------
#define SZ_C1 (2*NBATCH*BINS1)
#define OFF_C1 0
#define OFF_C2 (OFF_C1 + SZ_C1)
#define SZ_C3 (2*NBATCH*BINS3)
#define OFF_C3 (OFF_C2 + SZ_C1)
#define OFF_SUM3 (OFF_C3 + SZ_C3)      // f32 [2*64][1024] level-3 bin sums
#define OFF_STATE (OFF_SUM3 + SZ_C3)
#define ST_N     (OFF_STATE)        // u32 [128] masked count per (tensor,batch)
#define ST_N2    (ST_N + 128)       // u32 [128] #{x > median}
#define ST_B1    (ST_N2 + 128)      // u32 [128]
#define ST_B2    (ST_B1 + 128)      // u32 [128]
#define ST_RANK  (ST_B2 + 128)      // u32 [128]
#define ST_CLT   (ST_RANK + 128)    // u32 [128] count strictly below bucket
#define ST_SHIFT (ST_CLT + 128)     // f32 [128] median
#define ST_SCL   (ST_SHIFT + 128)   // f32 [128] robust scale
#define ST_STOT  (ST_SCL + 128)     // f32 [128] sum of masked x
#define ST_S1    (ST_STOT + 128)    // f32 [128] sum of masked x, level-1 bucket < b1
#define ST_S2    (ST_S1 + 128)      // f32 [128] sum of masked x, bucket==b1, mid < b2
#define ST_TSUM  (ST_S2 + 128)      // f32 [64]  residual sum (trim provably no-op)
#define ST_GSUM  (ST_TSUM + 64)     // f32 [4*64] gradient sums
#define ST_GCNT  (ST_GSUM + 256)    // u32 [4*64] gradient mask counts
#define WS_TOTAL (ST_GCNT + 256)

// gradient tile geometry: 128x64 interior, 136x72 loaded (right/bottom halo 8)
#define GTW 128
#define GTH 64
#define GHALO 8
#define GLW (GTW + GHALO)      // 136
#define GLH (GTH + GHALO)      // 72
#define GL4 (GLW/4)            // 34

// order-preserving float -> u32 key
__device__ __forceinline__ uint32_t fkey(float x) {
    uint32_t u = __float_as_uint(x);
    return (u & 0x80000000u) ? ~u : (u | 0x80000000u);
}
__device__ __forceinline__ float funkey(uint32_t k) {
    return __uint_as_float((k & 0x80000000u) ? (k & 0x7fffffffu) : ~k);
}
__device__ __forceinline__ float norm_diff(float p, float t, float sp, float ivp, float st, float ivt) {
    return (p - sp)*ivp - (t - st)*ivt;
}

// ===== medhist1: level-1 counts (mask = tgt>0) + streaming S_tot for both tensors =====
__global__ __launch_bounds__(256) void k_medhist1(const float* __restrict__ pred, const float* __restrict__ tgt,
                                                  uint32_t* __restrict__ cnt, float* __restrict__ stot) {
    __shared__ uint32_t cP[BINS1], cT[BINS1];
    __shared__ float redP[4], redT[4];
    const int tid = threadIdx.x;
    for (int i = tid; i < BINS1; i += 256) { cP[i]=0u; cT[i]=0u; }
    __syncthreads();
    const int b = blockIdx.y;
    const float4* p4 = (const float4*)pred;
    const float4* t4 = (const float4*)tgt;
    size_t base = (size_t)b*(NPIX/4) + (size_t)blockIdx.x*(NPIX/4/HGX);
    float aP = 0.f, aT = 0.f;
    for (int it = 0; it < HITER; it += 2) {   // unroll 2: 4 independent 16B loads in flight
        size_t i0 = base + (size_t)it*256 + tid;
        float4 pv0 = p4[i0], tv0 = t4[i0];
        float4 pv1 = p4[i0+256], tv1 = t4[i0+256];
        float pa[8] = {pv0.x,pv0.y,pv0.z,pv0.w, pv1.x,pv1.y,pv1.z,pv1.w};
        float ta[8] = {tv0.x,tv0.y,tv0.z,tv0.w, tv1.x,tv1.y,tv1.z,tv1.w};
#pragma unroll
        for (int j = 0; j < 8; ++j) {
            if (ta[j] > 0.f) {
                atomicAdd(&cP[fkey(pa[j]) >> 21], 1u);
                atomicAdd(&cT[fkey(ta[j]) >> 21], 1u);
                aP += pa[j]; aT += ta[j];
            }
        }
    }
    const int lane = tid & 63, wv = tid >> 6;
    for (int off = 32; off; off >>= 1) { aP += __shfl_down(aP, off, 64); aT += __shfl_down(aT, off, 64); }
    if (lane == 0) { redP[wv] = aP; redT[wv] = aT; }
    __syncthreads();
    if (tid == 0) atomicAdd(&stot[b],        redP[0]+redP[1]+redP[2]+redP[3]);
    if (tid == 1) atomicAdd(&stot[NBATCH+b], redT[0]+redT[1]+redT[2]+redT[3]);
    for (int i = tid; i < BINS1; i += 256) {
        if (cP[i]) atomicAdd(&cnt[(size_t)b*BINS1+i], cP[i]);
        if (cT[i]) atomicAdd(&cnt[(size_t)(NBATCH+b)*BINS1+i], cT[i]);
    }
}

// ===== medhist2: level-2 counts + streaming S1 (sum of x in buckets < b1) =====
__global__ __launch_bounds__(256) void k_medhist2(const float* __restrict__ pred, const float* __restrict__ tgt,
                                                  const uint32_t* __restrict__ b1arr,
                                                  uint32_t* __restrict__ cnt, float* __restrict__ s1arr) {
    __shared__ uint32_t cP[BINS2], cT[BINS2];
    __shared__ float redP[4], redT[4];
    const int tid = threadIdx.x;
    for (int i = tid; i < BINS2; i += 256) { cP[i]=0u; cT[i]=0u; }
    __syncthreads();
    const int b = blockIdx.y;
    const uint32_t b1p = b1arr[b], b1t = b1arr[NBATCH+b];
    const float4* p4 = (const float4*)pred;
    const float4* t4 = (const float4*)tgt;
    size_t base = (size_t)b*(NPIX/4) + (size_t)blockIdx.x*(NPIX/4/HGX);
    float aP = 0.f, aT = 0.f;
    for (int it = 0; it < HITER; it += 2) {
        size_t i0 = base + (size_t)it*256 + tid;
        float4 pv0 = p4[i0], tv0 = t4[i0];
        float4 pv1 = p4[i0+256], tv1 = t4[i0+256];
        float pa[8] = {pv0.x,pv0.y,pv0.z,pv0.w, pv1.x,pv1.y,pv1.z,pv1.w};
        float ta[8] = {tv0.x,tv0.y,tv0.z,tv0.w, tv1.x,tv1.y,tv1.z,tv1.w};
#pragma unroll
        for (int j = 0; j < 8; ++j) {
            if (ta[j] > 0.f) {
                uint32_t kp = fkey(pa[j]), kt = fkey(ta[j]);
                uint32_t hp = kp >> 21, ht = kt >> 21;
                if (hp == b1p) atomicAdd(&cP[(kp>>10)&2047u], 1u);
                else if (hp < b1p) aP += pa[j];
                if (ht == b1t) atomicAdd(&cT[(kt>>10)&2047u], 1u);
                else if (ht < b1t) aT += ta[j];
            }
        }
    }
    const int lane = tid & 63, wv = tid >> 6;
    for (int off = 32; off; off >>= 1) { aP += __shfl_down(aP, off, 64); aT += __shfl_down(aT, off, 64); }
    if (lane == 0) { redP[wv] = aP; redT[wv] = aT; }
    __syncthreads();
    if (tid == 0) atomicAdd(&s1arr[b],        redP[0]+redP[1]+redP[2]+redP[3]);
    if (tid == 1) atomicAdd(&s1arr[NBATCH+b], redT[0]+redT[1]+redT[2]+redT[3]);
    for (int i = tid; i < BINS2; i += 256) {
        if (cP[i]) atomicAdd(&cnt[(size_t)b*BINS2+i], cP[i]);
        if (cT[i]) atomicAdd(&cnt[(size_t)(NBATCH+b)*BINS2+i], cT[i]);
    }
}

// ===== medhist3: level-3 counts + SUMS (few elems -> cheap) + streaming S2 =====
__global__ __launch_bounds__(256) void k_medhist3(const float* __restrict__ pred, const float* __restrict__ tgt,
                                                  const uint32_t* __restrict__ b1arr, const uint32_t* __restrict__ b2arr,
                                                  uint32_t* __restrict__ cnt, float* __restrict__ sum3,
                                                  float* __restrict__ s2arr) {
    __shared__ uint32_t cP[BINS3], cT[BINS3];
    __shared__ float sSP[BINS3], sST[BINS3];
    __shared__ float redP[4], redT[4];
    const int tid = threadIdx.x;
    for (int i = tid; i < BINS3; i += 256) { cP[i]=0u; cT[i]=0u; sSP[i]=0.f; sST[i]=0.f; }
    __syncthreads();
    const int b = blockIdx.y;
    const uint32_t b1p = b1arr[b], b1t = b1arr[NBATCH+b];
    const uint32_t t22p = (b1p<<11) | b2arr[b];
    const uint32_t t22t = (b1t<<11) | b2arr[NBATCH+b];
    const float4* p4 = (const float4*)pred;
    const float4* t4 = (const float4*)tgt;
    size_t base = (size_t)b*(NPIX/4) + (size_t)blockIdx.x*(NPIX/4/HGX);
    float aP = 0.f, aT = 0.f;
    for (int it = 0; it < HITER; it += 2) {
        size_t i0 = base + (size_t)it*256 + tid;
        float4 pv0 = p4[i0], tv0 = t4[i0];
        float4 pv1 = p4[i0+256], tv1 = t4[i0+256];
        float pa[8] = {pv0.x,pv0.y,pv0.z,pv0.w, pv1.x,pv1.y,pv1.z,pv1.w};
        float ta[8] = {tv0.x,tv0.y,tv0.z,tv0.w, tv1.x,tv1.y,tv1.z,tv1.w};
#pragma unroll
        for (int j = 0; j < 8; ++j) {
            if (ta[j] > 0.f) {
                uint32_t kp = fkey(pa[j]), kt = fkey(ta[j]);
                if ((kp >> 10) == t22p) { atomicAdd(&cP[kp&1023u], 1u); atomicAdd(&sSP[kp&1023u], pa[j]); }
                else if ((kp >> 21) == b1p && (kp >> 10) < t22p) aP += pa[j];
                if ((kt >> 10) == t22t) { atomicAdd(&cT[kt&1023u], 1u); atomicAdd(&sST[kt&1023u], ta[j]); }
                else if ((kt >> 21) == b1t && (kt >> 10) < t22t) aT += ta[j];
            }
        }
    }
    const int lane = tid & 63, wv = tid >> 6;
    for (int off = 32; off; off >>= 1) { aP += __shfl_down(aP, off, 64); aT += __shfl_down(aT, off, 64); }
    if (lane == 0) { redP[wv] = aP; redT[wv] = aT; }
    __syncthreads();
    if (tid == 0) atomicAdd(&s2arr[b],        redP[0]+redP[1]+redP[2]+redP[3]);
    if (tid == 1) atomicAdd(&s2arr[NBATCH+b], redT[0]+redT[1]+redT[2]+redT[3]);
    for (int i = tid; i < BINS3; i += 256) {
        if (cP[i]) { atomicAdd(&cnt[(size_t)b*BINS3+i], cP[i]); atomicAdd(&sum3[(size_t)b*BINS3+i], sSP[i]); }
        if (cT[i]) { atomicAdd(&cnt[(size_t)(NBATCH+b)*BINS3+i], cT[i]); atomicAdd(&sum3[(size_t)(NBATCH+b)*BINS3+i], sST[i]); }
    }
}

// ===== generic level select (median path only). At level 2 also computes MAD scale. =====
__global__ __launch_bounds__(256) void k_select(uint32_t* wu, float* wf,
                                                const uint32_t* cnt, const float* sum3,
                                                int nbins, int level) {
    const int q = blockIdx.x;       // 128 problems: tensor*64+batch
    const int tid = threadIdx.x;
    const int bpt = nbins >> 8;
    const uint32_t* c  = cnt  + (size_t)q*nbins + (size_t)tid*bpt;
    const float*    s3 = sum3 + (size_t)q*nbins + (size_t)tid*bpt;
    uint32_t tcnt = 0; float tfs = 0.f;
    for (int j = 0; j < bpt; ++j) tcnt += c[j];
    if (level == 2) for (int j = 0; j < bpt; ++j) tfs += s3[j];
    __shared__ uint32_t sc[256];
    __shared__ float ss[256];
    sc[tid] = tcnt; ss[tid] = tfs;
    __syncthreads();
    for (int off = 1; off < 256; off <<= 1) {
        uint32_t u = 0; float f = 0.f;
        if (tid >= off) { u = sc[tid-off]; f = ss[tid-off]; }
        __syncthreads();
        if (tid >= off) { sc[tid] += u; ss[tid] += f; }
        __syncthreads();
    }
    const uint32_t total = sc[255];
    const uint32_t excl = sc[tid] - tcnt;
    const float exclS = ss[tid] - tfs;

    uint32_t r;
    if (level == 0) {
        if (tid == 0) wu[ST_N+q] = total;
        r = total ? (total - 1u) / 2u : 0u;   // lower median rank
    } else {
        r = wu[ST_RANK+q];
    }
    __syncthreads();  // all threads read ST_RANK before the owner overwrites it

    if (total > 0u && excl <= r && r < excl + tcnt) {
        uint32_t cum = excl; float fs = exclS;
        for (int j = 0; j < bpt; ++j) {
            uint32_t cj = c[j];
            if (r < cum + cj) {
                uint32_t bidx = (uint32_t)(tid*bpt + j);
                if (level == 0) {
                    wu[ST_B1+q] = bidx; wu[ST_RANK+q] = r - cum; wu[ST_CLT+q] = cum;
                } else if (level == 1) {
                    wu[ST_B2+q] = bidx; wu[ST_RANK+q] = r - cum; wu[ST_CLT+q] += cum;
                } else {
                    uint32_t key = (wu[ST_B1+q] << 21) | (wu[ST_B2+q] << 10) | bidx;
                    float m = funkey(key);                     // exact lower median
                    uint32_t n = wu[ST_N+q];
                    uint32_t c_le = wu[ST_CLT+q] + cum + cj;   // #{x <= m}
                    float S_le = wf[ST_S1+q] + wf[ST_S2+q] + fs + s3[j];
                    float madsum = (float)(2u*c_le - n) * m + wf[ST_STOT+q] - 2.f*S_le;
                    float scale = madsum / (float)(n ? n : 1u);
                    if (!(scale > 0.f)) scale = 1.f;           // ref: scale==0 -> 1
                    wf[ST_SHIFT+q] = m; wf[ST_SCL+q] = scale;
                    wu[ST_N2+q] = n - c_le;                    // #{x > median}
                }
                break;
            }
            cum += cj;
            if (level == 2) fs += s3[j];
        }
    }
    if (tid == 0 && total == 0u) {  // degenerate guard (no masked elements)
        if (level == 0)      { wu[ST_B1+q]=0; wu[ST_RANK+q]=0; wu[ST_CLT+q]=0; }
        else if (level == 1) { wu[ST_B2+q]=0; }
        else                 { wf[ST_SHIFT+q]=0.f; wf[ST_SCL+q]=1.f; wu[ST_N2+q]=0u; }
    }
}

// ===== fused 4-scale gradient loss + residual sum — dense per-scale, 512 threads =====
// Same 136x72 tile (39.2 KB LDS -> 4 blocks/CU) but 8 waves/block -> 32 waves/CU (100% occ).
__global__ __launch_bounds__(512) void k_grad(const float* __restrict__ pred, const float* __restrict__ tgt,
                                              const float* __restrict__ shiftA, const float* __restrict__ sclA,
                                              float* __restrict__ gsum, uint32_t* __restrict__ gcnt,
                                              float* __restrict__ tsum) {
    __shared__ float d_lds[GLH * GLW];
    const int b = blockIdx.y;
    const int bx = blockIdx.x & 3;       // 4 tiles across
    const int by = blockIdx.x >> 2;      // 8 tiles down
    const int x0 = bx * GTW, y0 = by * GTH;
    const int tid = threadIdx.x;
    const float sp = shiftA[b], st = shiftA[NBATCH+b];
    const float ivp = 1.f/sclA[b], ivt = 1.f/sclA[NBATCH+b];
    const float NANF = __int_as_float(0x7FC00000);

    const float4* p4 = (const float4*)pred;
    const float4* t4 = (const float4*)tgt;
    const size_t base4 = (size_t)b * (NPIX/4);

    // ---- load 136x72 tile (clamped halo never read back), compute d, stage to LDS ----
    for (int i = tid; i < GLH * GL4; i += 512) {
        const int r = i / GL4, c4 = i - r * GL4;
        int yg = y0 + r;  if (yg > HH-1) yg = HH-1;
        int c4g = (x0 >> 2) + c4;
        if (c4g > (WW >> 2) - 1) c4g = (WW >> 2) - 1;
        const size_t gidx = base4 + (size_t)yg * (WW/4) + c4g;
        const float4 pv = p4[gidx], tv = t4[gidx];
        float dd[4];
        dd[0] = (tv.x > st) ? norm_diff(pv.x, tv.x, sp, ivp, st, ivt) : NANF;
        dd[1] = (tv.y > st) ? norm_diff(pv.y, tv.y, sp, ivp, st, ivt) : NANF;
        dd[2] = (tv.z > st) ? norm_diff(pv.z, tv.z, sp, ivp, st, ivt) : NANF;
        dd[3] = (tv.w > st) ? norm_diff(pv.w, tv.w, sp, ivp, st, ivt) : NANF;
        *(float4*)&d_lds[r * GLW + c4 * 4] = *(float4*)dd;
    }
    __syncthreads();

    float gs[4] = {0.f,0.f,0.f,0.f};
    uint32_t gc[4] = {0u,0u,0u,0u};
    float ts = 0.f;

    // ---- scale 0 (s=1): dense, 16 px/thread + trim sum ----
    {
        const int xl = tid & (GTW - 1);
        const int yb = tid >> 7;             // 0..3
        const int xg = x0 + xl;
#pragma unroll 4
        for (int k = 0; k < GTH/4; ++k) {
            const int yl = yb + 4*k;
            const int yg = y0 + yl;
            const float d0 = d_lds[yl * GLW + xl];
            const bool m0 = (d0 == d0);
            if (m0) { ts += fabsf(d0); gc[0] += 1u; }
            if (xg + 1 < WW) {
                const float v = fabsf(d_lds[yl * GLW + xl + 1] - d0);
                if (v == v) gs[0] += v;
            }
            if (yg + 1 < HH) {
                const float v = fabsf(d_lds[(yl + 1) * GLW + xl] - d0);
                if (v == v) gs[0] += v;
            }
        }
    }
    // ---- scale 1 (s=2): 64x32 = 2048 active px, 4/thread ----
#pragma unroll
    for (int j = 0; j < 4; ++j) {
        const int i = tid + 512*j;
        const int xl = (i & 63) << 1, yl = (i >> 6) << 1;
        const int xg = x0 + xl, yg = y0 + yl;
        const float d0 = d_lds[yl * GLW + xl];
        if (d0 == d0) gc[1] += 1u;
        if (xg + 2 < WW) {
            const float v = fabsf(d_lds[yl * GLW + xl + 2] - d0);
            if (v == v) gs[1] += v;
        }
        if (yg + 2 < HH) {
            const float v = fabsf(d_lds[(yl + 2) * GLW + xl] - d0);
            if (v == v) gs[1] += v;
        }
    }
    // ---- scale 2 (s=4): 32x16 = 512 active px, 1/thread ----
    {
        const int xl = (tid & 31) << 2, yl = (tid >> 5) << 2;
        const int xg = x0 + xl, yg = y0 + yl;
        const float d0 = d_lds[yl * GLW + xl];
        if (d0 == d0) gc[2] += 1u;
        if (xg + 4 < WW) {
            const float v = fabsf(d_lds[yl * GLW + xl + 4] - d0);
            if (v == v) gs[2] += v;
        }
        if (yg + 4 < HH) {
            const float v = fabsf(d_lds[(yl + 4) * GLW + xl] - d0);
            if (v == v) gs[2] += v;
        }
    }
    // ---- scale 3 (s=8): 16x8 = 128 active px, threads < 128 ----
    if (tid < 128) {
        const int xl = (tid & 15) << 3, yl = (tid >> 4) << 3;
        const int xg = x0 + xl, yg = y0 + yl;
        const float d0 = d_lds[yl * GLW + xl];
        if (d0 == d0) gc[3] += 1u;
        if (xg + 8 < WW) {
            const float v = fabsf(d_lds[yl * GLW + xl + 8] - d0);
            if (v == v) gs[3] += v;
        }
        if (yg + 8 < HH) {
            const float v = fabsf(d_lds[(yl + 8) * GLW + xl] - d0);
            if (v == v) gs[3] += v;
        }
    }

    // ---- block reduce (8 waves) + global atomics ----
    __shared__ float ls[4][8];
    __shared__ uint32_t lc[4][8];
    __shared__ float lt[8];
    const int lane = tid & 63, wv = tid >> 6;
#pragma unroll
    for (int sL = 0; sL < 4; ++sL) {
        float v = gs[sL]; uint32_t cc = gc[sL];
        for (int off = 32; off; off >>= 1) { v += __shfl_down(v, off, 64); cc += __shfl_down(cc, off, 64); }
        if (lane == 0) { ls[sL][wv] = v; lc[sL][wv] = cc; }
    }
    for (int off = 32; off; off >>= 1) ts += __shfl_down(ts, off, 64);
    if (lane == 0) lt[wv] = ts;
    __syncthreads();
    if (tid < 4) {
        const int sL = tid;
        float v = 0.f; uint32_t cc = 0u;
#pragma unroll
        for (int w = 0; w < 8; ++w) { v += ls[sL][w]; cc += lc[sL][w]; }
        if (v != 0.f) atomicAdd(&gsum[sL*NBATCH + b], v);
        if (cc)       atomicAdd(&gcnt[sL*NBATCH + b], cc);
    }
    if (tid == 4) {
        float v = 0.f;
#pragma unroll
        for (int w = 0; w < 8; ++w) v += lt[w];
        if (v != 0.f) atomicAdd(&tsum[b], v);
    }
}

// ================= final combine =================
__global__ void k_final(const uint32_t* __restrict__ wu, const float* __restrict__ tsum,
                        const float* __restrict__ gsum, const uint32_t* __restrict__ gcnt,
                        float* __restrict__ out) {
    const int b = threadIdx.x;  // 64 threads, one wave
    uint32_t n2 = wu[ST_N2 + NBATCH + b];
    float v = n2 ? tsum[b] / (float)(2u*n2) : 0.f;
#pragma unroll
    for (int sL = 0; sL < 4; ++sL) {
        uint32_t cc = gcnt[sL*NBATCH + b];
        float g = cc ? gsum[sL*NBATCH + b] / (float)cc : 0.f;
        v += 0.5f * g;   // ALPHA = 0.5
    }
    for (int off = 32; off; off >>= 1) v += __shfl_down(v, off, 64);
    if (b == 0) out[0] = v * (1.f/64.f);
}

extern "C" void kernel_launch(void* const* d_in, const int* in_sizes, int n_in,
                              void* d_out, int out_size, void* d_ws, size_t ws_size,
                              hipStream_t stream) {
    const float* pred = (const float*)d_in[0];
    const float* tgt  = (const float*)d_in[1];
    uint32_t* wu = (uint32_t*)d_ws;
    float*    wf = (float*)d_ws;
    if (ws_size < (size_t)WS_TOTAL * 4) return;  // ~3.2 MB needed

    hipMemsetAsync(d_ws, 0, (size_t)WS_TOTAL * 4, stream);
    dim3 hg(HGX, NBATCH);

    // --- medians + analytic MAD scale (3-level radix select, sum-augmented level 3) ---
    k_medhist1<<<hg, 256, 0, stream>>>(pred, tgt, wu + OFF_C1, wf + ST_STOT);
    k_select<<<128, 256, 0, stream>>>(wu, wf, wu + OFF_C1, wf + OFF_SUM3, BINS1, 0);
    k_medhist2<<<hg, 256, 0, stream>>>(pred, tgt, wu + ST_B1, wu + OFF_C2, wf + ST_S1);
    k_select<<<128, 256, 0, stream>>>(wu, wf, wu + OFF_C2, wf + OFF_SUM3, BINS2, 1);
    k_medhist3<<<hg, 256, 0, stream>>>(pred, tgt, wu + ST_B1, wu + ST_B2, wu + OFF_C3,
                                       wf + OFF_SUM3, wf + ST_S2);
    k_select<<<128, 256, 0, stream>>>(wu, wf, wu + OFF_C3, wf + OFF_SUM3, BINS3, 2);

    // --- fused multiscale gradient loss + residual sum (tiled, dense, 512-thread) ---
    k_grad<<<dim3(32, NBATCH), 512, 0, stream>>>(pred, tgt, wf + ST_SHIFT, wf + ST_SCL,
                                                 wf + ST_GSUM, wu + ST_GCNT, wf + ST_TSUM);
    // --- combine ---
    k_final<<<1, 64, 0, stream>>>(wu, wf + ST_TSUM, wf + ST_GSUM, wu + ST_GCNT, (float*)d_out);
}

// Round 10
// 138.091 us; speedup vs baseline: 6.3994x; 1.2301x over previous
//
#include <hip/hip_runtime.h>
#include <stdint.h>

#define NBATCH 64
#define HH 512
#define WW 512
#define NPIX 262144            // 512*512
#define BINS1 2048             // key bits [31:21]
#define BINS2 2048             // key bits [20:10]
#define BINS3 1024             // key bits [9:0]
#define HGX 16                 // hist blocks per batch (512-thread blocks)
#define HITER (NPIX/4/HGX/512) // float4 iters per hist block (= 8)

// ---------------- workspace layout (u32 units) ----------------
#define SZ_C1 (2*NBATCH*BINS1)
#define OFF_C1 0
#define OFF_C2 (OFF_C1 + SZ_C1)
#define SZ_C3 (2*NBATCH*BINS3)
#define OFF_C3 (OFF_C2 + SZ_C1)
#define OFF_SUM3 (OFF_C3 + SZ_C3)      // f32 [2*64][1024] level-3 bin sums
#define OFF_STATE (OFF_SUM3 + SZ_C3)
#define ST_N     (OFF_STATE)        // u32 [128] masked count per (tensor,batch)
#define ST_N2    (ST_N + 128)       // u32 [128] #{x > median}
#define ST_B1    (ST_N2 + 128)      // u32 [128]
#define ST_B2    (ST_B1 + 128)      // u32 [128]
#define ST_RANK  (ST_B2 + 128)      // u32 [128]
#define ST_CLT   (ST_RANK + 128)    // u32 [128] count strictly below bucket
#define ST_SHIFT (ST_CLT + 128)     // f32 [128] median
#define ST_SCL   (ST_SHIFT + 128)   // f32 [128] robust scale
#define ST_STOT  (ST_SCL + 128)     // f32 [128] sum of masked x
#define ST_S1    (ST_STOT + 128)    // f32 [128] sum of masked x, level-1 bucket < b1
#define ST_S2    (ST_S1 + 128)      // f32 [128] sum of masked x, bucket==b1, mid < b2
#define ST_TSUM  (ST_S2 + 128)      // f32 [64]  residual sum (trim provably no-op)
#define ST_GSUM  (ST_TSUM + 64)     // f32 [4*64] gradient sums
#define ST_GCNT  (ST_GSUM + 256)    // u32 [4*64] gradient mask counts
#define WS_TOTAL (ST_GCNT + 256)

// gradient tile geometry: 128x64 interior, 136x72 loaded (right/bottom halo 8)
#define GTW 128
#define GTH 64
#define GHALO 8
#define GLW (GTW + GHALO)      // 136
#define GLH (GTH + GHALO)      // 72
#define GL4 (GLW/4)            // 34

// order-preserving float -> u32 key
__device__ __forceinline__ uint32_t fkey(float x) {
    uint32_t u = __float_as_uint(x);
    return (u & 0x80000000u) ? ~u : (u | 0x80000000u);
}
__device__ __forceinline__ float funkey(uint32_t k) {
    return __uint_as_float((k & 0x80000000u) ? (k & 0x7fffffffu) : ~k);
}
__device__ __forceinline__ float norm_diff(float p, float t, float sp, float ivp, float st, float ivt) {
    return (p - sp)*ivp - (t - st)*ivt;
}

// ===== medhist1: level-1 counts (mask = tgt>0) + streaming S_tot for both tensors =====
__global__ __launch_bounds__(512) void k_medhist1(const float* __restrict__ pred, const float* __restrict__ tgt,
                                                  uint32_t* __restrict__ cnt, float* __restrict__ stot) {
    __shared__ uint32_t cP[BINS1], cT[BINS1];
    __shared__ float redP[8], redT[8];
    const int tid = threadIdx.x;
    for (int i = tid; i < BINS1; i += 512) { cP[i]=0u; cT[i]=0u; }
    __syncthreads();
    const int b = blockIdx.y;
    const float4* p4 = (const float4*)pred;
    const float4* t4 = (const float4*)tgt;
    size_t base = (size_t)b*(NPIX/4) + (size_t)blockIdx.x*(NPIX/4/HGX);
    float aP = 0.f, aT = 0.f;
    for (int it = 0; it < HITER; it += 2) {   // unroll 2: 4 independent 16B loads in flight
        size_t i0 = base + (size_t)it*512 + tid;
        float4 pv0 = p4[i0], tv0 = t4[i0];
        float4 pv1 = p4[i0+512], tv1 = t4[i0+512];
        float pa[8] = {pv0.x,pv0.y,pv0.z,pv0.w, pv1.x,pv1.y,pv1.z,pv1.w};
        float ta[8] = {tv0.x,tv0.y,tv0.z,tv0.w, tv1.x,tv1.y,tv1.z,tv1.w};
#pragma unroll
        for (int j = 0; j < 8; ++j) {
            if (ta[j] > 0.f) {
                atomicAdd(&cP[fkey(pa[j]) >> 21], 1u);
                atomicAdd(&cT[fkey(ta[j]) >> 21], 1u);
                aP += pa[j]; aT += ta[j];
            }
        }
    }
    const int lane = tid & 63, wv = tid >> 6;
    for (int off = 32; off; off >>= 1) { aP += __shfl_down(aP, off, 64); aT += __shfl_down(aT, off, 64); }
    if (lane == 0) { redP[wv] = aP; redT[wv] = aT; }
    __syncthreads();
    if (tid == 0) { float s=0.f; for (int w=0;w<8;++w) s+=redP[w]; atomicAdd(&stot[b], s); }
    if (tid == 1) { float s=0.f; for (int w=0;w<8;++w) s+=redT[w]; atomicAdd(&stot[NBATCH+b], s); }
    for (int i = tid; i < BINS1; i += 512) {
        if (cP[i]) atomicAdd(&cnt[(size_t)b*BINS1+i], cP[i]);
        if (cT[i]) atomicAdd(&cnt[(size_t)(NBATCH+b)*BINS1+i], cT[i]);
    }
}

// ===== medhist2: level-2 counts + streaming S1 (sum of x in buckets < b1) =====
__global__ __launch_bounds__(512) void k_medhist2(const float* __restrict__ pred, const float* __restrict__ tgt,
                                                  const uint32_t* __restrict__ b1arr,
                                                  uint32_t* __restrict__ cnt, float* __restrict__ s1arr) {
    __shared__ uint32_t cP[BINS2], cT[BINS2];
    __shared__ float redP[8], redT[8];
    const int tid = threadIdx.x;
    for (int i = tid; i < BINS2; i += 512) { cP[i]=0u; cT[i]=0u; }
    __syncthreads();
    const int b = blockIdx.y;
    const uint32_t b1p = b1arr[b], b1t = b1arr[NBATCH+b];
    const float4* p4 = (const float4*)pred;
    const float4* t4 = (const float4*)tgt;
    size_t base = (size_t)b*(NPIX/4) + (size_t)blockIdx.x*(NPIX/4/HGX);
    float aP = 0.f, aT = 0.f;
    for (int it = 0; it < HITER; it += 2) {
        size_t i0 = base + (size_t)it*512 + tid;
        float4 pv0 = p4[i0], tv0 = t4[i0];
        float4 pv1 = p4[i0+512], tv1 = t4[i0+512];
        float pa[8] = {pv0.x,pv0.y,pv0.z,pv0.w, pv1.x,pv1.y,pv1.z,pv1.w};
        float ta[8] = {tv0.x,tv0.y,tv0.z,tv0.w, tv1.x,tv1.y,tv1.z,tv1.w};
#pragma unroll
        for (int j = 0; j < 8; ++j) {
            if (ta[j] > 0.f) {
                uint32_t kp = fkey(pa[j]), kt = fkey(ta[j]);
                uint32_t hp = kp >> 21, ht = kt >> 21;
                if (hp == b1p) atomicAdd(&cP[(kp>>10)&2047u], 1u);
                else if (hp < b1p) aP += pa[j];
                if (ht == b1t) atomicAdd(&cT[(kt>>10)&2047u], 1u);
                else if (ht < b1t) aT += ta[j];
            }
        }
    }
    const int lane = tid & 63, wv = tid >> 6;
    for (int off = 32; off; off >>= 1) { aP += __shfl_down(aP, off, 64); aT += __shfl_down(aT, off, 64); }
    if (lane == 0) { redP[wv] = aP; redT[wv] = aT; }
    __syncthreads();
    if (tid == 0) { float s=0.f; for (int w=0;w<8;++w) s+=redP[w]; atomicAdd(&s1arr[b], s); }
    if (tid == 1) { float s=0.f; for (int w=0;w<8;++w) s+=redT[w]; atomicAdd(&s1arr[NBATCH+b], s); }
    for (int i = tid; i < BINS2; i += 512) {
        if (cP[i]) atomicAdd(&cnt[(size_t)b*BINS2+i], cP[i]);
        if (cT[i]) atomicAdd(&cnt[(size_t)(NBATCH+b)*BINS2+i], cT[i]);
    }
}

// ===== medhist3: level-3 counts + SUMS (few elems -> cheap) + streaming S2 =====
__global__ __launch_bounds__(512) void k_medhist3(const float* __restrict__ pred, const float* __restrict__ tgt,
                                                  const uint32_t* __restrict__ b1arr, const uint32_t* __restrict__ b2arr,
                                                  uint32_t* __restrict__ cnt, float* __restrict__ sum3,
                                                  float* __restrict__ s2arr) {
    __shared__ uint32_t cP[BINS3], cT[BINS3];
    __shared__ float sSP[BINS3], sST[BINS3];
    __shared__ float redP[8], redT[8];
    const int tid = threadIdx.x;
    for (int i = tid; i < BINS3; i += 512) { cP[i]=0u; cT[i]=0u; sSP[i]=0.f; sST[i]=0.f; }
    __syncthreads();
    const int b = blockIdx.y;
    const uint32_t b1p = b1arr[b], b1t = b1arr[NBATCH+b];
    const uint32_t t22p = (b1p<<11) | b2arr[b];
    const uint32_t t22t = (b1t<<11) | b2arr[NBATCH+b];
    const float4* p4 = (const float4*)pred;
    const float4* t4 = (const float4*)tgt;
    size_t base = (size_t)b*(NPIX/4) + (size_t)blockIdx.x*(NPIX/4/HGX);
    float aP = 0.f, aT = 0.f;
    for (int it = 0; it < HITER; it += 2) {
        size_t i0 = base + (size_t)it*512 + tid;
        float4 pv0 = p4[i0], tv0 = t4[i0];
        float4 pv1 = p4[i0+512], tv1 = t4[i0+512];
        float pa[8] = {pv0.x,pv0.y,pv0.z,pv0.w, pv1.x,pv1.y,pv1.z,pv1.w};
        float ta[8] = {tv0.x,tv0.y,tv0.z,tv0.w, tv1.x,tv1.y,tv1.z,tv1.w};
#pragma unroll
        for (int j = 0; j < 8; ++j) {
            if (ta[j] > 0.f) {
                uint32_t kp = fkey(pa[j]), kt = fkey(ta[j]);
                if ((kp >> 10) == t22p) { atomicAdd(&cP[kp&1023u], 1u); atomicAdd(&sSP[kp&1023u], pa[j]); }
                else if ((kp >> 21) == b1p && (kp >> 10) < t22p) aP += pa[j];
                if ((kt >> 10) == t22t) { atomicAdd(&cT[kt&1023u], 1u); atomicAdd(&sST[kt&1023u], ta[j]); }
                else if ((kt >> 21) == b1t && (kt >> 10) < t22t) aT += ta[j];
            }
        }
    }
    const int lane = tid & 63, wv = tid >> 6;
    for (int off = 32; off; off >>= 1) { aP += __shfl_down(aP, off, 64); aT += __shfl_down(aT, off, 64); }
    if (lane == 0) { redP[wv] = aP; redT[wv] = aT; }
    __syncthreads();
    if (tid == 0) { float s=0.f; for (int w=0;w<8;++w) s+=redP[w]; atomicAdd(&s2arr[b], s); }
    if (tid == 1) { float s=0.f; for (int w=0;w<8;++w) s+=redT[w]; atomicAdd(&s2arr[NBATCH+b], s); }
    for (int i = tid; i < BINS3; i += 512) {
        if (cP[i]) { atomicAdd(&cnt[(size_t)b*BINS3+i], cP[i]); atomicAdd(&sum3[(size_t)b*BINS3+i], sSP[i]); }
        if (cT[i]) { atomicAdd(&cnt[(size_t)(NBATCH+b)*BINS3+i], cT[i]); atomicAdd(&sum3[(size_t)(NBATCH+b)*BINS3+i], sST[i]); }
    }
}

// ===== generic level select (median path only). At level 2 also computes MAD scale. =====
__global__ __launch_bounds__(256) void k_select(uint32_t* wu, float* wf,
                                                const uint32_t* cnt, const float* sum3,
                                                int nbins, int level) {
    const int q = blockIdx.x;       // 128 problems: tensor*64+batch
    const int tid = threadIdx.x;
    const int bpt = nbins >> 8;
    const uint32_t* c  = cnt  + (size_t)q*nbins + (size_t)tid*bpt;
    const float*    s3 = sum3 + (size_t)q*nbins + (size_t)tid*bpt;
    uint32_t tcnt = 0; float tfs = 0.f;
    for (int j = 0; j < bpt; ++j) tcnt += c[j];
    if (level == 2) for (int j = 0; j < bpt; ++j) tfs += s3[j];
    __shared__ uint32_t sc[256];
    __shared__ float ss[256];
    sc[tid] = tcnt; ss[tid] = tfs;
    __syncthreads();
    for (int off = 1; off < 256; off <<= 1) {
        uint32_t u = 0; float f = 0.f;
        if (tid >= off) { u = sc[tid-off]; f = ss[tid-off]; }
        __syncthreads();
        if (tid >= off) { sc[tid] += u; ss[tid] += f; }
        __syncthreads();
    }
    const uint32_t total = sc[255];
    const uint32_t excl = sc[tid] - tcnt;
    const float exclS = ss[tid] - tfs;

    uint32_t r;
    if (level == 0) {
        if (tid == 0) wu[ST_N+q] = total;
        r = total ? (total - 1u) / 2u : 0u;   // lower median rank
    } else {
        r = wu[ST_RANK+q];
    }
    __syncthreads();  // all threads read ST_RANK before the owner overwrites it

    if (total > 0u && excl <= r && r < excl + tcnt) {
        uint32_t cum = excl; float fs = exclS;
        for (int j = 0; j < bpt; ++j) {
            uint32_t cj = c[j];
            if (r < cum + cj) {
                uint32_t bidx = (uint32_t)(tid*bpt + j);
                if (level == 0) {
                    wu[ST_B1+q] = bidx; wu[ST_RANK+q] = r - cum; wu[ST_CLT+q] = cum;
                } else if (level == 1) {
                    wu[ST_B2+q] = bidx; wu[ST_RANK+q] = r - cum; wu[ST_CLT+q] += cum;
                } else {
                    uint32_t key = (wu[ST_B1+q] << 21) | (wu[ST_B2+q] << 10) | bidx;
                    float m = funkey(key);                     // exact lower median
                    uint32_t n = wu[ST_N+q];
                    uint32_t c_le = wu[ST_CLT+q] + cum + cj;   // #{x <= m}
                    float S_le = wf[ST_S1+q] + wf[ST_S2+q] + fs + s3[j];
                    float madsum = (float)(2u*c_le - n) * m + wf[ST_STOT+q] - 2.f*S_le;
                    float scale = madsum / (float)(n ? n : 1u);
                    if (!(scale > 0.f)) scale = 1.f;           // ref: scale==0 -> 1
                    wf[ST_SHIFT+q] = m; wf[ST_SCL+q] = scale;
                    wu[ST_N2+q] = n - c_le;                    // #{x > median}
                }
                break;
            }
            cum += cj;
            if (level == 2) fs += s3[j];
        }
    }
    if (tid == 0 && total == 0u) {  // degenerate guard (no masked elements)
        if (level == 0)      { wu[ST_B1+q]=0; wu[ST_RANK+q]=0; wu[ST_CLT+q]=0; }
        else if (level == 1) { wu[ST_B2+q]=0; }
        else                 { wf[ST_SHIFT+q]=0.f; wf[ST_SCL+q]=1.f; wu[ST_N2+q]=0u; }
    }
}

// ===== fused 4-scale gradient loss + residual sum — dense per-scale, 512 threads =====
// XCD-aware bijective block swizzle: each XCD gets a contiguous run of (batch,tile)
// ids so a batch's 32 tiles (with overlapping halos, shared 2MB input pair) stay on
// one XCD's L2. 2048 % 8 == 0 -> bijective.
__global__ __launch_bounds__(512) void k_grad(const float* __restrict__ pred, const float* __restrict__ tgt,
                                              const float* __restrict__ shiftA, const float* __restrict__ sclA,
                                              float* __restrict__ gsum, uint32_t* __restrict__ gcnt,
                                              float* __restrict__ tsum) {
    __shared__ float d_lds[GLH * GLW];
    const int bid0 = blockIdx.y * 32 + blockIdx.x;       // hw id (round-robin over XCDs)
    const int bid  = (bid0 & 7) * 256 + (bid0 >> 3);     // logical id, XCD-contiguous
    const int b    = bid >> 5;                            // batch
    const int tile = bid & 31;
    const int bx = tile & 3;             // 4 tiles across
    const int by = tile >> 2;            // 8 tiles down
    const int x0 = bx * GTW, y0 = by * GTH;
    const int tid = threadIdx.x;
    const float sp = shiftA[b], st = shiftA[NBATCH+b];
    const float ivp = 1.f/sclA[b], ivt = 1.f/sclA[NBATCH+b];
    const float NANF = __int_as_float(0x7FC00000);

    const float4* p4 = (const float4*)pred;
    const float4* t4 = (const float4*)tgt;
    const size_t base4 = (size_t)b * (NPIX/4);

    // ---- load 136x72 tile (clamped halo never read back), compute d, stage to LDS ----
    for (int i = tid; i < GLH * GL4; i += 512) {
        const int r = i / GL4, c4 = i - r * GL4;
        int yg = y0 + r;  if (yg > HH-1) yg = HH-1;
        int c4g = (x0 >> 2) + c4;
        if (c4g > (WW >> 2) - 1) c4g = (WW >> 2) - 1;
        const size_t gidx = base4 + (size_t)yg * (WW/4) + c4g;
        const float4 pv = p4[gidx], tv = t4[gidx];
        float dd[4];
        dd[0] = (tv.x > st) ? norm_diff(pv.x, tv.x, sp, ivp, st, ivt) : NANF;
        dd[1] = (tv.y > st) ? norm_diff(pv.y, tv.y, sp, ivp, st, ivt) : NANF;
        dd[2] = (tv.z > st) ? norm_diff(pv.z, tv.z, sp, ivp, st, ivt) : NANF;
        dd[3] = (tv.w > st) ? norm_diff(pv.w, tv.w, sp, ivp, st, ivt) : NANF;
        *(float4*)&d_lds[r * GLW + c4 * 4] = *(float4*)dd;
    }
    __syncthreads();

    float gs[4] = {0.f,0.f,0.f,0.f};
    uint32_t gc[4] = {0u,0u,0u,0u};
    float ts = 0.f;

    // ---- scale 0 (s=1): dense, 16 px/thread + trim sum ----
    {
        const int xl = tid & (GTW - 1);
        const int yb = tid >> 7;             // 0..3
        const int xg = x0 + xl;
#pragma unroll 4
        for (int k = 0; k < GTH/4; ++k) {
            const int yl = yb + 4*k;
            const int yg = y0 + yl;
            const float d0 = d_lds[yl * GLW + xl];
            const bool m0 = (d0 == d0);
            if (m0) { ts += fabsf(d0); gc[0] += 1u; }
            if (xg + 1 < WW) {
                const float v = fabsf(d_lds[yl * GLW + xl + 1] - d0);
                if (v == v) gs[0] += v;
            }
            if (yg + 1 < HH) {
                const float v = fabsf(d_lds[(yl + 1) * GLW + xl] - d0);
                if (v == v) gs[0] += v;
            }
        }
    }
    // ---- scale 1 (s=2): 64x32 = 2048 active px, 4/thread ----
#pragma unroll
    for (int j = 0; j < 4; ++j) {
        const int i = tid + 512*j;
        const int xl = (i & 63) << 1, yl = (i >> 6) << 1;
        const int xg = x0 + xl, yg = y0 + yl;
        const float d0 = d_lds[yl * GLW + xl];
        if (d0 == d0) gc[1] += 1u;
        if (xg + 2 < WW) {
            const float v = fabsf(d_lds[yl * GLW + xl + 2] - d0);
            if (v == v) gs[1] += v;
        }
        if (yg + 2 < HH) {
            const float v = fabsf(d_lds[(yl + 2) * GLW + xl] - d0);
            if (v == v) gs[1] += v;
        }
    }
    // ---- scale 2 (s=4): 32x16 = 512 active px, 1/thread ----
    {
        const int xl = (tid & 31) << 2, yl = (tid >> 5) << 2;
        const int xg = x0 + xl, yg = y0 + yl;
        const float d0 = d_lds[yl * GLW + xl];
        if (d0 == d0) gc[2] += 1u;
        if (xg + 4 < WW) {
            const float v = fabsf(d_lds[yl * GLW + xl + 4] - d0);
            if (v == v) gs[2] += v;
        }
        if (yg + 4 < HH) {
            const float v = fabsf(d_lds[(yl + 4) * GLW + xl] - d0);
            if (v == v) gs[2] += v;
        }
    }
    // ---- scale 3 (s=8): 16x8 = 128 active px, threads < 128 ----
    if (tid < 128) {
        const int xl = (tid & 15) << 3, yl = (tid >> 4) << 3;
        const int xg = x0 + xl, yg = y0 + yl;
        const float d0 = d_lds[yl * GLW + xl];
        if (d0 == d0) gc[3] += 1u;
        if (xg + 8 < WW) {
            const float v = fabsf(d_lds[yl * GLW + xl + 8] - d0);
            if (v == v) gs[3] += v;
        }
        if (yg + 8 < HH) {
            const float v = fabsf(d_lds[(yl + 8) * GLW + xl] - d0);
            if (v == v) gs[3] += v;
        }
    }

    // ---- block reduce (8 waves) + global atomics ----
    __shared__ float ls[4][8];
    __shared__ uint32_t lc[4][8];
    __shared__ float lt[8];
    const int lane = tid & 63, wv = tid >> 6;
#pragma unroll
    for (int sL = 0; sL < 4; ++sL) {
        float v = gs[sL]; uint32_t cc = gc[sL];
        for (int off = 32; off; off >>= 1) { v += __shfl_down(v, off, 64); cc += __shfl_down(cc, off, 64); }
        if (lane == 0) { ls[sL][wv] = v; lc[sL][wv] = cc; }
    }
    for (int off = 32; off; off >>= 1) ts += __shfl_down(ts, off, 64);
    if (lane == 0) lt[wv] = ts;
    __syncthreads();
    if (tid < 4) {
        const int sL = tid;
        float v = 0.f; uint32_t cc = 0u;
#pragma unroll
        for (int w = 0; w < 8; ++w) { v += ls[sL][w]; cc += lc[sL][w]; }
        if (v != 0.f) atomicAdd(&gsum[sL*NBATCH + b], v);
        if (cc)       atomicAdd(&gcnt[sL*NBATCH + b], cc);
    }
    if (tid == 4) {
        float v = 0.f;
#pragma unroll
        for (int w = 0; w < 8; ++w) v += lt[w];
        if (v != 0.f) atomicAdd(&tsum[b], v);
    }
}

// ================= final combine =================
__global__ void k_final(const uint32_t* __restrict__ wu, const float* __restrict__ tsum,
                        const float* __restrict__ gsum, const uint32_t* __restrict__ gcnt,
                        float* __restrict__ out) {
    const int b = threadIdx.x;  // 64 threads, one wave
    uint32_t n2 = wu[ST_N2 + NBATCH + b];
    float v = n2 ? tsum[b] / (float)(2u*n2) : 0.f;
#pragma unroll
    for (int sL = 0; sL < 4; ++sL) {
        uint32_t cc = gcnt[sL*NBATCH + b];
        float g = cc ? gsum[sL*NBATCH + b] / (float)cc : 0.f;
        v += 0.5f * g;   // ALPHA = 0.5
    }
    for (int off = 32; off; off >>= 1) v += __shfl_down(v, off, 64);
    if (b == 0) out[0] = v * (1.f/64.f);
}

extern "C" void kernel_launch(void* const* d_in, const int* in_sizes, int n_in,
                              void* d_out, int out_size, void* d_ws, size_t ws_size,
                              hipStream_t stream) {
    const float* pred = (const float*)d_in[0];
    const float* tgt  = (const float*)d_in[1];
    uint32_t* wu = (uint32_t*)d_ws;
    float*    wf = (float*)d_ws;
    if (ws_size < (size_t)WS_TOTAL * 4) return;  // ~3.2 MB needed

    hipMemsetAsync(d_ws, 0, (size_t)WS_TOTAL * 4, stream);
    dim3 hg(HGX, NBATCH);

    // --- medians + analytic MAD scale (3-level radix select, sum-augmented level 3) ---
    k_medhist1<<<hg, 512, 0, stream>>>(pred, tgt, wu + OFF_C1, wf + ST_STOT);
    k_select<<<128, 256, 0, stream>>>(wu, wf, wu + OFF_C1, wf + OFF_SUM3, BINS1, 0);
    k_medhist2<<<hg, 512, 0, stream>>>(pred, tgt, wu + ST_B1, wu + OFF_C2, wf + ST_S1);
    k_select<<<128, 256, 0, stream>>>(wu, wf, wu + OFF_C2, wf + OFF_SUM3, BINS2, 1);
    k_medhist3<<<hg, 512, 0, stream>>>(pred, tgt, wu + ST_B1, wu + ST_B2, wu + OFF_C3,
                                       wf + OFF_SUM3, wf + ST_S2);
    k_select<<<128, 256, 0, stream>>>(wu, wf, wu + OFF_C3, wf + OFF_SUM3, BINS3, 2);

    // --- fused multiscale gradient loss + residual sum (tiled, dense, 512-thread, XCD-swizzled) ---
    k_grad<<<dim3(32, NBATCH), 512, 0, stream>>>(pred, tgt, wf + ST_SHIFT, wf + ST_SCL,
                                                 wf + ST_GSUM, wu + ST_GCNT, wf + ST_TSUM);
    // --- combine ---
    k_final<<<1, 64, 0, stream>>>(wu, wf + ST_TSUM, wf + ST_GSUM, wu + ST_GCNT, (float*)d_out);
}

// Round 11
// 137.549 us; speedup vs baseline: 6.4246x; 1.0039x over previous
//
#include <hip/hip_runtime.h>
#include <stdint.h>

#define NBATCH 64
#define HH 512
#define WW 512
#define NPIX 262144            // 512*512
#define BINS1 2048             // key bits [31:21]
#define BINS2 2048             // key bits [20:10]
#define BINS3 1024             // key bits [9:0]
#define HGX 16                 // hist blocks per batch (512-thread blocks)
#define HITER (NPIX/4/HGX/512) // float4 iters per hist block (= 8)

// ---------------- workspace layout (u32 units) ----------------
#define SZ_C1 (2*NBATCH*BINS1)
#define OFF_C1 0
#define OFF_C2 (OFF_C1 + SZ_C1)
#define SZ_C3 (2*NBATCH*BINS3)
#define OFF_C3 (OFF_C2 + SZ_C1)
#define OFF_SUM3 (OFF_C3 + SZ_C3)      // f32 [2*64][1024] level-3 bin sums
#define OFF_STATE (OFF_SUM3 + SZ_C3)
#define ST_N     (OFF_STATE)        // u32 [128] masked count per (tensor,batch)
#define ST_N2    (ST_N + 128)       // u32 [128] #{x > median}
#define ST_B1    (ST_N2 + 128)      // u32 [128]
#define ST_B2    (ST_B1 + 128)      // u32 [128]
#define ST_RANK  (ST_B2 + 128)      // u32 [128]
#define ST_CLT   (ST_RANK + 128)    // u32 [128] count strictly below bucket
#define ST_SHIFT (ST_CLT + 128)     // f32 [128] median
#define ST_SCL   (ST_SHIFT + 128)   // f32 [128] robust scale
#define ST_STOT  (ST_SCL + 128)     // f32 [128] sum of masked x
#define ST_S1    (ST_STOT + 128)    // f32 [128] sum of masked x, level-1 bucket < b1
#define ST_S2    (ST_S1 + 128)      // f32 [128] sum of masked x, bucket==b1, mid < b2
#define ST_TSUM  (ST_S2 + 128)      // f32 [64]  residual sum (trim provably no-op)
#define ST_GSUM  (ST_TSUM + 64)     // f32 [4*64] gradient sums
#define ST_GCNT  (ST_GSUM + 256)    // u32 [4*64] gradient mask counts
#define WS_TOTAL (ST_GCNT + 256)

// gradient tile geometry: 128x64 interior, 136x72 loaded (right/bottom halo 8)
#define GTW 128
#define GTH 64
#define GHALO 8
#define GLW (GTW + GHALO)      // 136
#define GLH (GTH + GHALO)      // 72
#define GL4 (GLW/4)            // 34

// order-preserving float -> u32 key
__device__ __forceinline__ uint32_t fkey(float x) {
    uint32_t u = __float_as_uint(x);
    return (u & 0x80000000u) ? ~u : (u | 0x80000000u);
}
__device__ __forceinline__ float funkey(uint32_t k) {
    return __uint_as_float((k & 0x80000000u) ? (k & 0x7fffffffu) : ~k);
}
__device__ __forceinline__ float norm_diff(float p, float t, float sp, float ivp, float st, float ivt) {
    return (p - sp)*ivp - (t - st)*ivt;
}

// ===== medhist1: level-1 counts (mask = tgt>0) + streaming S_tot for both tensors =====
// 2 histogram replicas per block (wave-group private) -> 8 copies/CU at 4 blocks/CU,
// restoring r9's contention level with half the block overhead.
__global__ __launch_bounds__(512, 8) void k_medhist1(const float* __restrict__ pred, const float* __restrict__ tgt,
                                                     uint32_t* __restrict__ cnt, float* __restrict__ stot) {
    __shared__ uint32_t cP[2][BINS1], cT[2][BINS1];
    __shared__ float redP[8], redT[8];
    const int tid = threadIdx.x;
    const int rep = tid >> 8;            // waves 0-3 -> 0, waves 4-7 -> 1
    for (int i = tid; i < 2*BINS1; i += 512) { cP[0][i]=0u; cT[0][i]=0u; }   // flat zero both replicas
    __syncthreads();
    const int b = blockIdx.y;
    const float4* p4 = (const float4*)pred;
    const float4* t4 = (const float4*)tgt;
    size_t base = (size_t)b*(NPIX/4) + (size_t)blockIdx.x*(NPIX/4/HGX);
    float aP = 0.f, aT = 0.f;
    for (int it = 0; it < HITER; it += 2) {   // unroll 2: 4 independent 16B loads in flight
        size_t i0 = base + (size_t)it*512 + tid;
        float4 pv0 = p4[i0], tv0 = t4[i0];
        float4 pv1 = p4[i0+512], tv1 = t4[i0+512];
        float pa[8] = {pv0.x,pv0.y,pv0.z,pv0.w, pv1.x,pv1.y,pv1.z,pv1.w};
        float ta[8] = {tv0.x,tv0.y,tv0.z,tv0.w, tv1.x,tv1.y,tv1.z,tv1.w};
#pragma unroll
        for (int j = 0; j < 8; ++j) {
            if (ta[j] > 0.f) {
                atomicAdd(&cP[rep][fkey(pa[j]) >> 21], 1u);
                atomicAdd(&cT[rep][fkey(ta[j]) >> 21], 1u);
                aP += pa[j]; aT += ta[j];
            }
        }
    }
    const int lane = tid & 63, wv = tid >> 6;
    for (int off = 32; off; off >>= 1) { aP += __shfl_down(aP, off, 64); aT += __shfl_down(aT, off, 64); }
    if (lane == 0) { redP[wv] = aP; redT[wv] = aT; }
    __syncthreads();
    if (tid == 0) { float s=0.f; for (int w=0;w<8;++w) s+=redP[w]; atomicAdd(&stot[b], s); }
    if (tid == 1) { float s=0.f; for (int w=0;w<8;++w) s+=redT[w]; atomicAdd(&stot[NBATCH+b], s); }
    for (int i = tid; i < BINS1; i += 512) {
        uint32_t vP = cP[0][i] + cP[1][i];
        uint32_t vT = cT[0][i] + cT[1][i];
        if (vP) atomicAdd(&cnt[(size_t)b*BINS1+i], vP);
        if (vT) atomicAdd(&cnt[(size_t)(NBATCH+b)*BINS1+i], vT);
    }
}

// ===== medhist2: level-2 counts + streaming S1 (sum of x in buckets < b1) =====
__global__ __launch_bounds__(512, 8) void k_medhist2(const float* __restrict__ pred, const float* __restrict__ tgt,
                                                     const uint32_t* __restrict__ b1arr,
                                                     uint32_t* __restrict__ cnt, float* __restrict__ s1arr) {
    __shared__ uint32_t cP[BINS2], cT[BINS2];
    __shared__ float redP[8], redT[8];
    const int tid = threadIdx.x;
    for (int i = tid; i < BINS2; i += 512) { cP[i]=0u; cT[i]=0u; }
    __syncthreads();
    const int b = blockIdx.y;
    const uint32_t b1p = b1arr[b], b1t = b1arr[NBATCH+b];
    const float4* p4 = (const float4*)pred;
    const float4* t4 = (const float4*)tgt;
    size_t base = (size_t)b*(NPIX/4) + (size_t)blockIdx.x*(NPIX/4/HGX);
    float aP = 0.f, aT = 0.f;
    for (int it = 0; it < HITER; it += 2) {
        size_t i0 = base + (size_t)it*512 + tid;
        float4 pv0 = p4[i0], tv0 = t4[i0];
        float4 pv1 = p4[i0+512], tv1 = t4[i0+512];
        float pa[8] = {pv0.x,pv0.y,pv0.z,pv0.w, pv1.x,pv1.y,pv1.z,pv1.w};
        float ta[8] = {tv0.x,tv0.y,tv0.z,tv0.w, tv1.x,tv1.y,tv1.z,tv1.w};
#pragma unroll
        for (int j = 0; j < 8; ++j) {
            if (ta[j] > 0.f) {
                uint32_t kp = fkey(pa[j]), kt = fkey(ta[j]);
                uint32_t hp = kp >> 21, ht = kt >> 21;
                if (hp == b1p) atomicAdd(&cP[(kp>>10)&2047u], 1u);
                else if (hp < b1p) aP += pa[j];
                if (ht == b1t) atomicAdd(&cT[(kt>>10)&2047u], 1u);
                else if (ht < b1t) aT += ta[j];
            }
        }
    }
    const int lane = tid & 63, wv = tid >> 6;
    for (int off = 32; off; off >>= 1) { aP += __shfl_down(aP, off, 64); aT += __shfl_down(aT, off, 64); }
    if (lane == 0) { redP[wv] = aP; redT[wv] = aT; }
    __syncthreads();
    if (tid == 0) { float s=0.f; for (int w=0;w<8;++w) s+=redP[w]; atomicAdd(&s1arr[b], s); }
    if (tid == 1) { float s=0.f; for (int w=0;w<8;++w) s+=redT[w]; atomicAdd(&s1arr[NBATCH+b], s); }
    for (int i = tid; i < BINS2; i += 512) {
        if (cP[i]) atomicAdd(&cnt[(size_t)b*BINS2+i], cP[i]);
        if (cT[i]) atomicAdd(&cnt[(size_t)(NBATCH+b)*BINS2+i], cT[i]);
    }
}

// ===== medhist3: level-3 counts + SUMS (few elems -> cheap) + streaming S2 =====
__global__ __launch_bounds__(512, 8) void k_medhist3(const float* __restrict__ pred, const float* __restrict__ tgt,
                                                     const uint32_t* __restrict__ b1arr, const uint32_t* __restrict__ b2arr,
                                                     uint32_t* __restrict__ cnt, float* __restrict__ sum3,
                                                     float* __restrict__ s2arr) {
    __shared__ uint32_t cP[BINS3], cT[BINS3];
    __shared__ float sSP[BINS3], sST[BINS3];
    __shared__ float redP[8], redT[8];
    const int tid = threadIdx.x;
    for (int i = tid; i < BINS3; i += 512) { cP[i]=0u; cT[i]=0u; sSP[i]=0.f; sST[i]=0.f; }
    __syncthreads();
    const int b = blockIdx.y;
    const uint32_t b1p = b1arr[b], b1t = b1arr[NBATCH+b];
    const uint32_t t22p = (b1p<<11) | b2arr[b];
    const uint32_t t22t = (b1t<<11) | b2arr[NBATCH+b];
    const float4* p4 = (const float4*)pred;
    const float4* t4 = (const float4*)tgt;
    size_t base = (size_t)b*(NPIX/4) + (size_t)blockIdx.x*(NPIX/4/HGX);
    float aP = 0.f, aT = 0.f;
    for (int it = 0; it < HITER; it += 2) {
        size_t i0 = base + (size_t)it*512 + tid;
        float4 pv0 = p4[i0], tv0 = t4[i0];
        float4 pv1 = p4[i0+512], tv1 = t4[i0+512];
        float pa[8] = {pv0.x,pv0.y,pv0.z,pv0.w, pv1.x,pv1.y,pv1.z,pv1.w};
        float ta[8] = {tv0.x,tv0.y,tv0.z,tv0.w, tv1.x,tv1.y,tv1.z,tv1.w};
#pragma unroll
        for (int j = 0; j < 8; ++j) {
            if (ta[j] > 0.f) {
                uint32_t kp = fkey(pa[j]), kt = fkey(ta[j]);
                if ((kp >> 10) == t22p) { atomicAdd(&cP[kp&1023u], 1u); atomicAdd(&sSP[kp&1023u], pa[j]); }
                else if ((kp >> 21) == b1p && (kp >> 10) < t22p) aP += pa[j];
                if ((kt >> 10) == t22t) { atomicAdd(&cT[kt&1023u], 1u); atomicAdd(&sST[kt&1023u], ta[j]); }
                else if ((kt >> 21) == b1t && (kt >> 10) < t22t) aT += ta[j];
            }
        }
    }
    const int lane = tid & 63, wv = tid >> 6;
    for (int off = 32; off; off >>= 1) { aP += __shfl_down(aP, off, 64); aT += __shfl_down(aT, off, 64); }
    if (lane == 0) { redP[wv] = aP; redT[wv] = aT; }
    __syncthreads();
    if (tid == 0) { float s=0.f; for (int w=0;w<8;++w) s+=redP[w]; atomicAdd(&s2arr[b], s); }
    if (tid == 1) { float s=0.f; for (int w=0;w<8;++w) s+=redT[w]; atomicAdd(&s2arr[NBATCH+b], s); }
    for (int i = tid; i < BINS3; i += 512) {
        if (cP[i]) { atomicAdd(&cnt[(size_t)b*BINS3+i], cP[i]); atomicAdd(&sum3[(size_t)b*BINS3+i], sSP[i]); }
        if (cT[i]) { atomicAdd(&cnt[(size_t)(NBATCH+b)*BINS3+i], cT[i]); atomicAdd(&sum3[(size_t)(NBATCH+b)*BINS3+i], sST[i]); }
    }
}

// ===== generic level select (median path only). At level 2 also computes MAD scale. =====
__global__ __launch_bounds__(256) void k_select(uint32_t* wu, float* wf,
                                                const uint32_t* cnt, const float* sum3,
                                                int nbins, int level) {
    const int q = blockIdx.x;       // 128 problems: tensor*64+batch
    const int tid = threadIdx.x;
    const int bpt = nbins >> 8;
    const uint32_t* c  = cnt  + (size_t)q*nbins + (size_t)tid*bpt;
    const float*    s3 = sum3 + (size_t)q*nbins + (size_t)tid*bpt;
    uint32_t tcnt = 0; float tfs = 0.f;
    for (int j = 0; j < bpt; ++j) tcnt += c[j];
    if (level == 2) for (int j = 0; j < bpt; ++j) tfs += s3[j];
    __shared__ uint32_t sc[256];
    __shared__ float ss[256];
    sc[tid] = tcnt; ss[tid] = tfs;
    __syncthreads();
    for (int off = 1; off < 256; off <<= 1) {
        uint32_t u = 0; float f = 0.f;
        if (tid >= off) { u = sc[tid-off]; f = ss[tid-off]; }
        __syncthreads();
        if (tid >= off) { sc[tid] += u; ss[tid] += f; }
        __syncthreads();
    }
    const uint32_t total = sc[255];
    const uint32_t excl = sc[tid] - tcnt;
    const float exclS = ss[tid] - tfs;

    uint32_t r;
    if (level == 0) {
        if (tid == 0) wu[ST_N+q] = total;
        r = total ? (total - 1u) / 2u : 0u;   // lower median rank
    } else {
        r = wu[ST_RANK+q];
    }
    __syncthreads();  // all threads read ST_RANK before the owner overwrites it

    if (total > 0u && excl <= r && r < excl + tcnt) {
        uint32_t cum = excl; float fs = exclS;
        for (int j = 0; j < bpt; ++j) {
            uint32_t cj = c[j];
            if (r < cum + cj) {
                uint32_t bidx = (uint32_t)(tid*bpt + j);
                if (level == 0) {
                    wu[ST_B1+q] = bidx; wu[ST_RANK+q] = r - cum; wu[ST_CLT+q] = cum;
                } else if (level == 1) {
                    wu[ST_B2+q] = bidx; wu[ST_RANK+q] = r - cum; wu[ST_CLT+q] += cum;
                } else {
                    uint32_t key = (wu[ST_B1+q] << 21) | (wu[ST_B2+q] << 10) | bidx;
                    float m = funkey(key);                     // exact lower median
                    uint32_t n = wu[ST_N+q];
                    uint32_t c_le = wu[ST_CLT+q] + cum + cj;   // #{x <= m}
                    float S_le = wf[ST_S1+q] + wf[ST_S2+q] + fs + s3[j];
                    float madsum = (float)(2u*c_le - n) * m + wf[ST_STOT+q] - 2.f*S_le;
                    float scale = madsum / (float)(n ? n : 1u);
                    if (!(scale > 0.f)) scale = 1.f;           // ref: scale==0 -> 1
                    wf[ST_SHIFT+q] = m; wf[ST_SCL+q] = scale;
                    wu[ST_N2+q] = n - c_le;                    // #{x > median}
                }
                break;
            }
            cum += cj;
            if (level == 2) fs += s3[j];
        }
    }
    if (tid == 0 && total == 0u) {  // degenerate guard (no masked elements)
        if (level == 0)      { wu[ST_B1+q]=0; wu[ST_RANK+q]=0; wu[ST_CLT+q]=0; }
        else if (level == 1) { wu[ST_B2+q]=0; }
        else                 { wf[ST_SHIFT+q]=0.f; wf[ST_SCL+q]=1.f; wu[ST_N2+q]=0u; }
    }
}

// ===== fused 4-scale gradient loss + residual sum — dense per-scale, 512 threads =====
// XCD-aware bijective block swizzle (2048 % 8 == 0).
__global__ __launch_bounds__(512, 8) void k_grad(const float* __restrict__ pred, const float* __restrict__ tgt,
                                                 const float* __restrict__ shiftA, const float* __restrict__ sclA,
                                                 float* __restrict__ gsum, uint32_t* __restrict__ gcnt,
                                                 float* __restrict__ tsum) {
    __shared__ float d_lds[GLH * GLW];
    const int bid0 = blockIdx.y * 32 + blockIdx.x;       // hw id (round-robin over XCDs)
    const int bid  = (bid0 & 7) * 256 + (bid0 >> 3);     // logical id, XCD-contiguous
    const int b    = bid >> 5;                            // batch
    const int tile = bid & 31;
    const int bx = tile & 3;             // 4 tiles across
    const int by = tile >> 2;            // 8 tiles down
    const int x0 = bx * GTW, y0 = by * GTH;
    const int tid = threadIdx.x;
    const float sp = shiftA[b], st = shiftA[NBATCH+b];
    const float ivp = 1.f/sclA[b], ivt = 1.f/sclA[NBATCH+b];
    const float NANF = __int_as_float(0x7FC00000);

    const float4* p4 = (const float4*)pred;
    const float4* t4 = (const float4*)tgt;
    const size_t base4 = (size_t)b * (NPIX/4);

    // ---- load 136x72 tile (clamped halo never read back), compute d, stage to LDS ----
    for (int i = tid; i < GLH * GL4; i += 512) {
        const int r = i / GL4, c4 = i - r * GL4;
        int yg = y0 + r;  if (yg > HH-1) yg = HH-1;
        int c4g = (x0 >> 2) + c4;
        if (c4g > (WW >> 2) - 1) c4g = (WW >> 2) - 1;
        const size_t gidx = base4 + (size_t)yg * (WW/4) + c4g;
        const float4 pv = p4[gidx], tv = t4[gidx];
        float dd[4];
        dd[0] = (tv.x > st) ? norm_diff(pv.x, tv.x, sp, ivp, st, ivt) : NANF;
        dd[1] = (tv.y > st) ? norm_diff(pv.y, tv.y, sp, ivp, st, ivt) : NANF;
        dd[2] = (tv.z > st) ? norm_diff(pv.z, tv.z, sp, ivp, st, ivt) : NANF;
        dd[3] = (tv.w > st) ? norm_diff(pv.w, tv.w, sp, ivp, st, ivt) : NANF;
        *(float4*)&d_lds[r * GLW + c4 * 4] = *(float4*)dd;
    }
    __syncthreads();

    float gs[4] = {0.f,0.f,0.f,0.f};
    uint32_t gc[4] = {0u,0u,0u,0u};
    float ts = 0.f;

    // ---- scale 0 (s=1): dense, 16 px/thread + trim sum ----
    {
        const int xl = tid & (GTW - 1);
        const int yb = tid >> 7;             // 0..3
        const int xg = x0 + xl;
#pragma unroll 4
        for (int k = 0; k < GTH/4; ++k) {
            const int yl = yb + 4*k;
            const int yg = y0 + yl;
            const float d0 = d_lds[yl * GLW + xl];
            const bool m0 = (d0 == d0);
            if (m0) { ts += fabsf(d0); gc[0] += 1u; }
            if (xg + 1 < WW) {
                const float v = fabsf(d_lds[yl * GLW + xl + 1] - d0);
                if (v == v) gs[0] += v;
            }
            if (yg + 1 < HH) {
                const float v = fabsf(d_lds[(yl + 1) * GLW + xl] - d0);
                if (v == v) gs[0] += v;
            }
        }
    }
    // ---- scale 1 (s=2): 64x32 = 2048 active px, 4/thread ----
#pragma unroll
    for (int j = 0; j < 4; ++j) {
        const int i = tid + 512*j;
        const int xl = (i & 63) << 1, yl = (i >> 6) << 1;
        const int xg = x0 + xl, yg = y0 + yl;
        const float d0 = d_lds[yl * GLW + xl];
        if (d0 == d0) gc[1] += 1u;
        if (xg + 2 < WW) {
            const float v = fabsf(d_lds[yl * GLW + xl + 2] - d0);
            if (v == v) gs[1] += v;
        }
        if (yg + 2 < HH) {
            const float v = fabsf(d_lds[(yl + 2) * GLW + xl] - d0);
            if (v == v) gs[1] += v;
        }
    }
    // ---- scale 2 (s=4): 32x16 = 512 active px, 1/thread ----
    {
        const int xl = (tid & 31) << 2, yl = (tid >> 5) << 2;
        const int xg = x0 + xl, yg = y0 + yl;
        const float d0 = d_lds[yl * GLW + xl];
        if (d0 == d0) gc[2] += 1u;
        if (xg + 4 < WW) {
            const float v = fabsf(d_lds[yl * GLW + xl + 4] - d0);
            if (v == v) gs[2] += v;
        }
        if (yg + 4 < HH) {
            const float v = fabsf(d_lds[(yl + 4) * GLW + xl] - d0);
            if (v == v) gs[2] += v;
        }
    }
    // ---- scale 3 (s=8): 16x8 = 128 active px, threads < 128 ----
    if (tid < 128) {
        const int xl = (tid & 15) << 3, yl = (tid >> 4) << 3;
        const int xg = x0 + xl, yg = y0 + yl;
        const float d0 = d_lds[yl * GLW + xl];
        if (d0 == d0) gc[3] += 1u;
        if (xg + 8 < WW) {
            const float v = fabsf(d_lds[yl * GLW + xl + 8] - d0);
            if (v == v) gs[3] += v;
        }
        if (yg + 8 < HH) {
            const float v = fabsf(d_lds[(yl + 8) * GLW + xl] - d0);
            if (v == v) gs[3] += v;
        }
    }

    // ---- block reduce (8 waves) + global atomics ----
    __shared__ float ls[4][8];
    __shared__ uint32_t lc[4][8];
    __shared__ float lt[8];
    const int lane = tid & 63, wv = tid >> 6;
#pragma unroll
    for (int sL = 0; sL < 4; ++sL) {
        float v = gs[sL]; uint32_t cc = gc[sL];
        for (int off = 32; off; off >>= 1) { v += __shfl_down(v, off, 64); cc += __shfl_down(cc, off, 64); }
        if (lane == 0) { ls[sL][wv] = v; lc[sL][wv] = cc; }
    }
    for (int off = 32; off; off >>= 1) ts += __shfl_down(ts, off, 64);
    if (lane == 0) lt[wv] = ts;
    __syncthreads();
    if (tid < 4) {
        const int sL = tid;
        float v = 0.f; uint32_t cc = 0u;
#pragma unroll
        for (int w = 0; w < 8; ++w) { v += ls[sL][w]; cc += lc[sL][w]; }
        if (v != 0.f) atomicAdd(&gsum[sL*NBATCH + b], v);
        if (cc)       atomicAdd(&gcnt[sL*NBATCH + b], cc);
    }
    if (tid == 4) {
        float v = 0.f;
#pragma unroll
        for (int w = 0; w < 8; ++w) v += lt[w];
        if (v != 0.f) atomicAdd(&tsum[b], v);
    }
}

// ================= final combine =================
__global__ void k_final(const uint32_t* __restrict__ wu, const float* __restrict__ tsum,
                        const float* __restrict__ gsum, const uint32_t* __restrict__ gcnt,
                        float* __restrict__ out) {
    const int b = threadIdx.x;  // 64 threads, one wave
    uint32_t n2 = wu[ST_N2 + NBATCH + b];
    float v = n2 ? tsum[b] / (float)(2u*n2) : 0.f;
#pragma unroll
    for (int sL = 0; sL < 4; ++sL) {
        uint32_t cc = gcnt[sL*NBATCH + b];
        float g = cc ? gsum[sL*NBATCH + b] / (float)cc : 0.f;
        v += 0.5f * g;   // ALPHA = 0.5
    }
    for (int off = 32; off; off >>= 1) v += __shfl_down(v, off, 64);
    if (b == 0) out[0] = v * (1.f/64.f);
}

extern "C" void kernel_launch(void* const* d_in, const int* in_sizes, int n_in,
                              void* d_out, int out_size, void* d_ws, size_t ws_size,
                              hipStream_t stream) {
    const float* pred = (const float*)d_in[0];
    const float* tgt  = (const float*)d_in[1];
    uint32_t* wu = (uint32_t*)d_ws;
    float*    wf = (float*)d_ws;
    if (ws_size < (size_t)WS_TOTAL * 4) return;  // ~3.2 MB needed

    hipMemsetAsync(d_ws, 0, (size_t)WS_TOTAL * 4, stream);
    dim3 hg(HGX, NBATCH);

    // --- medians + analytic MAD scale (3-level radix select, sum-augmented level 3) ---
    k_medhist1<<<hg, 512, 0, stream>>>(pred, tgt, wu + OFF_C1, wf + ST_STOT);
    k_select<<<128, 256, 0, stream>>>(wu, wf, wu + OFF_C1, wf + OFF_SUM3, BINS1, 0);
    k_medhist2<<<hg, 512, 0, stream>>>(pred, tgt, wu + ST_B1, wu + OFF_C2, wf + ST_S1);
    k_select<<<128, 256, 0, stream>>>(wu, wf, wu + OFF_C2, wf + OFF_SUM3, BINS2, 1);
    k_medhist3<<<hg, 512, 0, stream>>>(pred, tgt, wu + ST_B1, wu + ST_B2, wu + OFF_C3,
                                       wf + OFF_SUM3, wf + ST_S2);
    k_select<<<128, 256, 0, stream>>>(wu, wf, wu + OFF_C3, wf + OFF_SUM3, BINS3, 2);

    // --- fused multiscale gradient loss + residual sum (tiled, dense, 512-thread, XCD-swizzled) ---
    k_grad<<<dim3(32, NBATCH), 512, 0, stream>>>(pred, tgt, wf + ST_SHIFT, wf + ST_SCL,
                                                 wf + ST_GSUM, wu + ST_GCNT, wf + ST_TSUM);
    // --- combine ---
    k_final<<<1, 64, 0, stream>>>(wu, wf + ST_TSUM, wf + ST_GSUM, wu + ST_GCNT, (float*)d_out);
}

// Round 12
// 135.517 us; speedup vs baseline: 6.5210x; 1.0150x over previous
//
#include <hip/hip_runtime.h>
#include <stdint.h>

#define NBATCH 64
#define HH 512
#define WW 512
#define NPIX 262144            // 512*512
#define BINS1 2048             // key bits [31:21]
#define BINS2 2048             // key bits [20:10]
#define BINS3 1024             // key bits [9:0]
#define HGX 16                 // hist blocks per batch (512-thread blocks)
#define HITER (NPIX/4/HGX/512) // float4 iters per hist block (= 8)
#define B1PAD (BINS1+1)        // +1 word so replica 1 lands on the adjacent bank

// ---------------- workspace layout (u32 units) ----------------
#define SZ_C1 (2*NBATCH*BINS1)
#define OFF_C1 0
#define OFF_C2 (OFF_C1 + SZ_C1)
#define SZ_C3 (2*NBATCH*BINS3)
#define OFF_C3 (OFF_C2 + SZ_C1)
#define OFF_SUM3 (OFF_C3 + SZ_C3)      // f32 [2*64][1024] level-3 bin sums
#define OFF_STATE (OFF_SUM3 + SZ_C3)
#define ST_N     (OFF_STATE)        // u32 [128] masked count per (tensor,batch)
#define ST_N2    (ST_N + 128)       // u32 [128] #{x > median}
#define ST_B1    (ST_N2 + 128)      // u32 [128]
#define ST_B2    (ST_B1 + 128)      // u32 [128]
#define ST_RANK  (ST_B2 + 128)      // u32 [128]
#define ST_CLT   (ST_RANK + 128)    // u32 [128] count strictly below bucket
#define ST_SHIFT (ST_CLT + 128)     // f32 [128] median
#define ST_SCL   (ST_SHIFT + 128)   // f32 [128] robust scale
#define ST_STOT  (ST_SCL + 128)     // f32 [128] sum of masked x
#define ST_S1    (ST_STOT + 128)    // f32 [128] sum of masked x, level-1 bucket < b1
#define ST_S2    (ST_S1 + 128)      // f32 [128] sum of masked x, bucket==b1, mid < b2
#define ST_TSUM  (ST_S2 + 128)      // f32 [64]  residual sum (trim provably no-op)
#define ST_GSUM  (ST_TSUM + 64)     // f32 [4*64] gradient sums
#define ST_GCNT  (ST_GSUM + 256)    // u32 [4*64] gradient mask counts
#define WS_TOTAL (ST_GCNT + 256)

// gradient tile geometry: 128x64 interior, 136x72 loaded (right/bottom halo 8)
#define GTW 128
#define GTH 64
#define GHALO 8
#define GLW (GTW + GHALO)      // 136
#define GLH (GTH + GHALO)      // 72
#define GL4 (GLW/4)            // 34

// order-preserving float -> u32 key
__device__ __forceinline__ uint32_t fkey(float x) {
    uint32_t u = __float_as_uint(x);
    return (u & 0x80000000u) ? ~u : (u | 0x80000000u);
}
__device__ __forceinline__ float funkey(uint32_t k) {
    return __uint_as_float((k & 0x80000000u) ? (k & 0x7fffffffu) : ~k);
}
__device__ __forceinline__ float norm_diff(float p, float t, float sp, float ivp, float st, float ivt) {
    return (p - sp)*ivp - (t - st)*ivt;
}

// ===== medhist1: level-1 counts (mask = tgt>0) + streaming S_tot for both tensors =====
// LANE-PARITY replicas (rep = tid&1) with +1-word pad: same-bin lanes inside a wave
// split 4+4 across two ADJACENT banks -> intra-wave same-address atomic serialization
// halves. LDS 32.8 KB -> 4 blocks/CU, 32 waves.
__global__ __launch_bounds__(512, 8) void k_medhist1(const float* __restrict__ pred, const float* __restrict__ tgt,
                                                     uint32_t* __restrict__ cnt, float* __restrict__ stot) {
    __shared__ uint32_t cP[2][B1PAD], cT[2][B1PAD];
    __shared__ float redP[8], redT[8];
    const int tid = threadIdx.x;
    const int rep = tid & 1;             // lane parity -> replica (intra-wave split)
    for (int i = tid; i < 2*B1PAD; i += 512) { (&cP[0][0])[i]=0u; (&cT[0][0])[i]=0u; }
    __syncthreads();
    const int b = blockIdx.y;
    const float4* p4 = (const float4*)pred;
    const float4* t4 = (const float4*)tgt;
    size_t base = (size_t)b*(NPIX/4) + (size_t)blockIdx.x*(NPIX/4/HGX);
    float aP = 0.f, aT = 0.f;
    for (int it = 0; it < HITER; it += 2) {   // unroll 2: 4 independent 16B loads in flight
        size_t i0 = base + (size_t)it*512 + tid;
        float4 pv0 = p4[i0], tv0 = t4[i0];
        float4 pv1 = p4[i0+512], tv1 = t4[i0+512];
        float pa[8] = {pv0.x,pv0.y,pv0.z,pv0.w, pv1.x,pv1.y,pv1.z,pv1.w};
        float ta[8] = {tv0.x,tv0.y,tv0.z,tv0.w, tv1.x,tv1.y,tv1.z,tv1.w};
#pragma unroll
        for (int j = 0; j < 8; ++j) {
            if (ta[j] > 0.f) {
                atomicAdd(&cP[rep][fkey(pa[j]) >> 21], 1u);
                atomicAdd(&cT[rep][fkey(ta[j]) >> 21], 1u);
                aP += pa[j]; aT += ta[j];
            }
        }
    }
    const int lane = tid & 63, wv = tid >> 6;
    for (int off = 32; off; off >>= 1) { aP += __shfl_down(aP, off, 64); aT += __shfl_down(aT, off, 64); }
    if (lane == 0) { redP[wv] = aP; redT[wv] = aT; }
    __syncthreads();
    if (tid == 0) { float s=0.f; for (int w=0;w<8;++w) s+=redP[w]; atomicAdd(&stot[b], s); }
    if (tid == 1) { float s=0.f; for (int w=0;w<8;++w) s+=redT[w]; atomicAdd(&stot[NBATCH+b], s); }
    for (int i = tid; i < BINS1; i += 512) {
        uint32_t vP = cP[0][i] + cP[1][i];
        uint32_t vT = cT[0][i] + cT[1][i];
        if (vP) atomicAdd(&cnt[(size_t)b*BINS1+i], vP);
        if (vT) atomicAdd(&cnt[(size_t)(NBATCH+b)*BINS1+i], vT);
    }
}

// ===== medhist2: level-2 counts + streaming S1 (sum of x in buckets < b1) =====
__global__ __launch_bounds__(512, 8) void k_medhist2(const float* __restrict__ pred, const float* __restrict__ tgt,
                                                     const uint32_t* __restrict__ b1arr,
                                                     uint32_t* __restrict__ cnt, float* __restrict__ s1arr) {
    __shared__ uint32_t cP[BINS2], cT[BINS2];
    __shared__ float redP[8], redT[8];
    const int tid = threadIdx.x;
    for (int i = tid; i < BINS2; i += 512) { cP[i]=0u; cT[i]=0u; }
    __syncthreads();
    const int b = blockIdx.y;
    const uint32_t b1p = b1arr[b], b1t = b1arr[NBATCH+b];
    const float4* p4 = (const float4*)pred;
    const float4* t4 = (const float4*)tgt;
    size_t base = (size_t)b*(NPIX/4) + (size_t)blockIdx.x*(NPIX/4/HGX);
    float aP = 0.f, aT = 0.f;
    for (int it = 0; it < HITER; it += 2) {
        size_t i0 = base + (size_t)it*512 + tid;
        float4 pv0 = p4[i0], tv0 = t4[i0];
        float4 pv1 = p4[i0+512], tv1 = t4[i0+512];
        float pa[8] = {pv0.x,pv0.y,pv0.z,pv0.w, pv1.x,pv1.y,pv1.z,pv1.w};
        float ta[8] = {tv0.x,tv0.y,tv0.z,tv0.w, tv1.x,tv1.y,tv1.z,tv1.w};
#pragma unroll
        for (int j = 0; j < 8; ++j) {
            if (ta[j] > 0.f) {
                uint32_t kp = fkey(pa[j]), kt = fkey(ta[j]);
                uint32_t hp = kp >> 21, ht = kt >> 21;
                if (hp == b1p) atomicAdd(&cP[(kp>>10)&2047u], 1u);
                else if (hp < b1p) aP += pa[j];
                if (ht == b1t) atomicAdd(&cT[(kt>>10)&2047u], 1u);
                else if (ht < b1t) aT += ta[j];
            }
        }
    }
    const int lane = tid & 63, wv = tid >> 6;
    for (int off = 32; off; off >>= 1) { aP += __shfl_down(aP, off, 64); aT += __shfl_down(aT, off, 64); }
    if (lane == 0) { redP[wv] = aP; redT[wv] = aT; }
    __syncthreads();
    if (tid == 0) { float s=0.f; for (int w=0;w<8;++w) s+=redP[w]; atomicAdd(&s1arr[b], s); }
    if (tid == 1) { float s=0.f; for (int w=0;w<8;++w) s+=redT[w]; atomicAdd(&s1arr[NBATCH+b], s); }
    for (int i = tid; i < BINS2; i += 512) {
        if (cP[i]) atomicAdd(&cnt[(size_t)b*BINS2+i], cP[i]);
        if (cT[i]) atomicAdd(&cnt[(size_t)(NBATCH+b)*BINS2+i], cT[i]);
    }
}

// ===== medhist3: level-3 counts + SUMS (few elems -> cheap) + streaming S2 =====
__global__ __launch_bounds__(512, 8) void k_medhist3(const float* __restrict__ pred, const float* __restrict__ tgt,
                                                     const uint32_t* __restrict__ b1arr, const uint32_t* __restrict__ b2arr,
                                                     uint32_t* __restrict__ cnt, float* __restrict__ sum3,
                                                     float* __restrict__ s2arr) {
    __shared__ uint32_t cP[BINS3], cT[BINS3];
    __shared__ float sSP[BINS3], sST[BINS3];
    __shared__ float redP[8], redT[8];
    const int tid = threadIdx.x;
    for (int i = tid; i < BINS3; i += 512) { cP[i]=0u; cT[i]=0u; sSP[i]=0.f; sST[i]=0.f; }
    __syncthreads();
    const int b = blockIdx.y;
    const uint32_t b1p = b1arr[b], b1t = b1arr[NBATCH+b];
    const uint32_t t22p = (b1p<<11) | b2arr[b];
    const uint32_t t22t = (b1t<<11) | b2arr[NBATCH+b];
    const float4* p4 = (const float4*)pred;
    const float4* t4 = (const float4*)tgt;
    size_t base = (size_t)b*(NPIX/4) + (size_t)blockIdx.x*(NPIX/4/HGX);
    float aP = 0.f, aT = 0.f;
    for (int it = 0; it < HITER; it += 2) {
        size_t i0 = base + (size_t)it*512 + tid;
        float4 pv0 = p4[i0], tv0 = t4[i0];
        float4 pv1 = p4[i0+512], tv1 = t4[i0+512];
        float pa[8] = {pv0.x,pv0.y,pv0.z,pv0.w, pv1.x,pv1.y,pv1.z,pv1.w};
        float ta[8] = {tv0.x,tv0.y,tv0.z,tv0.w, tv1.x,tv1.y,tv1.z,tv1.w};
#pragma unroll
        for (int j = 0; j < 8; ++j) {
            if (ta[j] > 0.f) {
                uint32_t kp = fkey(pa[j]), kt = fkey(ta[j]);
                if ((kp >> 10) == t22p) { atomicAdd(&cP[kp&1023u], 1u); atomicAdd(&sSP[kp&1023u], pa[j]); }
                else if ((kp >> 21) == b1p && (kp >> 10) < t22p) aP += pa[j];
                if ((kt >> 10) == t22t) { atomicAdd(&cT[kt&1023u], 1u); atomicAdd(&sST[kt&1023u], ta[j]); }
                else if ((kt >> 21) == b1t && (kt >> 10) < t22t) aT += ta[j];
            }
        }
    }
    const int lane = tid & 63, wv = tid >> 6;
    for (int off = 32; off; off >>= 1) { aP += __shfl_down(aP, off, 64); aT += __shfl_down(aT, off, 64); }
    if (lane == 0) { redP[wv] = aP; redT[wv] = aT; }
    __syncthreads();
    if (tid == 0) { float s=0.f; for (int w=0;w<8;++w) s+=redP[w]; atomicAdd(&s2arr[b], s); }
    if (tid == 1) { float s=0.f; for (int w=0;w<8;++w) s+=redT[w]; atomicAdd(&s2arr[NBATCH+b], s); }
    for (int i = tid; i < BINS3; i += 512) {
        if (cP[i]) { atomicAdd(&cnt[(size_t)b*BINS3+i], cP[i]); atomicAdd(&sum3[(size_t)b*BINS3+i], sSP[i]); }
        if (cT[i]) { atomicAdd(&cnt[(size_t)(NBATCH+b)*BINS3+i], cT[i]); atomicAdd(&sum3[(size_t)(NBATCH+b)*BINS3+i], sST[i]); }
    }
}

// ===== generic level select (median path only). At level 2 also computes MAD scale. =====
__global__ __launch_bounds__(256) void k_select(uint32_t* wu, float* wf,
                                                const uint32_t* cnt, const float* sum3,
                                                int nbins, int level) {
    const int q = blockIdx.x;       // 128 problems: tensor*64+batch
    const int tid = threadIdx.x;
    const int bpt = nbins >> 8;
    const uint32_t* c  = cnt  + (size_t)q*nbins + (size_t)tid*bpt;
    const float*    s3 = sum3 + (size_t)q*nbins + (size_t)tid*bpt;
    uint32_t tcnt = 0; float tfs = 0.f;
    for (int j = 0; j < bpt; ++j) tcnt += c[j];
    if (level == 2) for (int j = 0; j < bpt; ++j) tfs += s3[j];
    __shared__ uint32_t sc[256];
    __shared__ float ss[256];
    sc[tid] = tcnt; ss[tid] = tfs;
    __syncthreads();
    for (int off = 1; off < 256; off <<= 1) {
        uint32_t u = 0; float f = 0.f;
        if (tid >= off) { u = sc[tid-off]; f = ss[tid-off]; }
        __syncthreads();
        if (tid >= off) { sc[tid] += u; ss[tid] += f; }
        __syncthreads();
    }
    const uint32_t total = sc[255];
    const uint32_t excl = sc[tid] - tcnt;
    const float exclS = ss[tid] - tfs;

    uint32_t r;
    if (level == 0) {
        if (tid == 0) wu[ST_N+q] = total;
        r = total ? (total - 1u) / 2u : 0u;   // lower median rank
    } else {
        r = wu[ST_RANK+q];
    }
    __syncthreads();  // all threads read ST_RANK before the owner overwrites it

    if (total > 0u && excl <= r && r < excl + tcnt) {
        uint32_t cum = excl; float fs = exclS;
        for (int j = 0; j < bpt; ++j) {
            uint32_t cj = c[j];
            if (r < cum + cj) {
                uint32_t bidx = (uint32_t)(tid*bpt + j);
                if (level == 0) {
                    wu[ST_B1+q] = bidx; wu[ST_RANK+q] = r - cum; wu[ST_CLT+q] = cum;
                } else if (level == 1) {
                    wu[ST_B2+q] = bidx; wu[ST_RANK+q] = r - cum; wu[ST_CLT+q] += cum;
                } else {
                    uint32_t key = (wu[ST_B1+q] << 21) | (wu[ST_B2+q] << 10) | bidx;
                    float m = funkey(key);                     // exact lower median
                    uint32_t n = wu[ST_N+q];
                    uint32_t c_le = wu[ST_CLT+q] + cum + cj;   // #{x <= m}
                    float S_le = wf[ST_S1+q] + wf[ST_S2+q] + fs + s3[j];
                    float madsum = (float)(2u*c_le - n) * m + wf[ST_STOT+q] - 2.f*S_le;
                    float scale = madsum / (float)(n ? n : 1u);
                    if (!(scale > 0.f)) scale = 1.f;           // ref: scale==0 -> 1
                    wf[ST_SHIFT+q] = m; wf[ST_SCL+q] = scale;
                    wu[ST_N2+q] = n - c_le;                    // #{x > median}
                }
                break;
            }
            cum += cj;
            if (level == 2) fs += s3[j];
        }
    }
    if (tid == 0 && total == 0u) {  // degenerate guard (no masked elements)
        if (level == 0)      { wu[ST_B1+q]=0; wu[ST_RANK+q]=0; wu[ST_CLT+q]=0; }
        else if (level == 1) { wu[ST_B2+q]=0; }
        else                 { wf[ST_SHIFT+q]=0.f; wf[ST_SCL+q]=1.f; wu[ST_N2+q]=0u; }
    }
}

// ===== fused 4-scale gradient loss + residual sum — dense per-scale, 512 threads =====
// XCD-aware bijective block swizzle (2048 % 8 == 0).
__global__ __launch_bounds__(512, 8) void k_grad(const float* __restrict__ pred, const float* __restrict__ tgt,
                                                 const float* __restrict__ shiftA, const float* __restrict__ sclA,
                                                 float* __restrict__ gsum, uint32_t* __restrict__ gcnt,
                                                 float* __restrict__ tsum) {
    __shared__ float d_lds[GLH * GLW];
    const int bid0 = blockIdx.y * 32 + blockIdx.x;       // hw id (round-robin over XCDs)
    const int bid  = (bid0 & 7) * 256 + (bid0 >> 3);     // logical id, XCD-contiguous
    const int b    = bid >> 5;                            // batch
    const int tile = bid & 31;
    const int bx = tile & 3;             // 4 tiles across
    const int by = tile >> 2;            // 8 tiles down
    const int x0 = bx * GTW, y0 = by * GTH;
    const int tid = threadIdx.x;
    const float sp = shiftA[b], st = shiftA[NBATCH+b];
    const float ivp = 1.f/sclA[b], ivt = 1.f/sclA[NBATCH+b];
    const float NANF = __int_as_float(0x7FC00000);

    const float4* p4 = (const float4*)pred;
    const float4* t4 = (const float4*)tgt;
    const size_t base4 = (size_t)b * (NPIX/4);

    // ---- load 136x72 tile (clamped halo never read back), compute d, stage to LDS ----
    for (int i = tid; i < GLH * GL4; i += 512) {
        const int r = i / GL4, c4 = i - r * GL4;
        int yg = y0 + r;  if (yg > HH-1) yg = HH-1;
        int c4g = (x0 >> 2) + c4;
        if (c4g > (WW >> 2) - 1) c4g = (WW >> 2) - 1;
        const size_t gidx = base4 + (size_t)yg * (WW/4) + c4g;
        const float4 pv = p4[gidx], tv = t4[gidx];
        float dd[4];
        dd[0] = (tv.x > st) ? norm_diff(pv.x, tv.x, sp, ivp, st, ivt) : NANF;
        dd[1] = (tv.y > st) ? norm_diff(pv.y, tv.y, sp, ivp, st, ivt) : NANF;
        dd[2] = (tv.z > st) ? norm_diff(pv.z, tv.z, sp, ivp, st, ivt) : NANF;
        dd[3] = (tv.w > st) ? norm_diff(pv.w, tv.w, sp, ivp, st, ivt) : NANF;
        *(float4*)&d_lds[r * GLW + c4 * 4] = *(float4*)dd;
    }
    __syncthreads();

    float gs[4] = {0.f,0.f,0.f,0.f};
    uint32_t gc[4] = {0u,0u,0u,0u};
    float ts = 0.f;

    // ---- scale 0 (s=1): dense, 16 px/thread + trim sum ----
    {
        const int xl = tid & (GTW - 1);
        const int yb = tid >> 7;             // 0..3
        const int xg = x0 + xl;
#pragma unroll 4
        for (int k = 0; k < GTH/4; ++k) {
            const int yl = yb + 4*k;
            const int yg = y0 + yl;
            const float d0 = d_lds[yl * GLW + xl];
            const bool m0 = (d0 == d0);
            if (m0) { ts += fabsf(d0); gc[0] += 1u; }
            if (xg + 1 < WW) {
                const float v = fabsf(d_lds[yl * GLW + xl + 1] - d0);
                if (v == v) gs[0] += v;
            }
            if (yg + 1 < HH) {
                const float v = fabsf(d_lds[(yl + 1) * GLW + xl] - d0);
                if (v == v) gs[0] += v;
            }
        }
    }
    // ---- scale 1 (s=2): 64x32 = 2048 active px, 4/thread ----
#pragma unroll
    for (int j = 0; j < 4; ++j) {
        const int i = tid + 512*j;
        const int xl = (i & 63) << 1, yl = (i >> 6) << 1;
        const int xg = x0 + xl, yg = y0 + yl;
        const float d0 = d_lds[yl * GLW + xl];
        if (d0 == d0) gc[1] += 1u;
        if (xg + 2 < WW) {
            const float v = fabsf(d_lds[yl * GLW + xl + 2] - d0);
            if (v == v) gs[1] += v;
        }
        if (yg + 2 < HH) {
            const float v = fabsf(d_lds[(yl + 2) * GLW + xl] - d0);
            if (v == v) gs[1] += v;
        }
    }
    // ---- scale 2 (s=4): 32x16 = 512 active px, 1/thread ----
    {
        const int xl = (tid & 31) << 2, yl = (tid >> 5) << 2;
        const int xg = x0 + xl, yg = y0 + yl;
        const float d0 = d_lds[yl * GLW + xl];
        if (d0 == d0) gc[2] += 1u;
        if (xg + 4 < WW) {
            const float v = fabsf(d_lds[yl * GLW + xl + 4] - d0);
            if (v == v) gs[2] += v;
        }
        if (yg + 4 < HH) {
            const float v = fabsf(d_lds[(yl + 4) * GLW + xl] - d0);
            if (v == v) gs[2] += v;
        }
    }
    // ---- scale 3 (s=8): 16x8 = 128 active px, threads < 128 ----
    if (tid < 128) {
        const int xl = (tid & 15) << 3, yl = (tid >> 4) << 3;
        const int xg = x0 + xl, yg = y0 + yl;
        const float d0 = d_lds[yl * GLW + xl];
        if (d0 == d0) gc[3] += 1u;
        if (xg + 8 < WW) {
            const float v = fabsf(d_lds[yl * GLW + xl + 8] - d0);
            if (v == v) gs[3] += v;
        }
        if (yg + 8 < HH) {
            const float v = fabsf(d_lds[(yl + 8) * GLW + xl] - d0);
            if (v == v) gs[3] += v;
        }
    }

    // ---- block reduce (8 waves) + global atomics ----
    __shared__ float ls[4][8];
    __shared__ uint32_t lc[4][8];
    __shared__ float lt[8];
    const int lane = tid & 63, wv = tid >> 6;
#pragma unroll
    for (int sL = 0; sL < 4; ++sL) {
        float v = gs[sL]; uint32_t cc = gc[sL];
        for (int off = 32; off; off >>= 1) { v += __shfl_down(v, off, 64); cc += __shfl_down(cc, off, 64); }
        if (lane == 0) { ls[sL][wv] = v; lc[sL][wv] = cc; }
    }
    for (int off = 32; off; off >>= 1) ts += __shfl_down(ts, off, 64);
    if (lane == 0) lt[wv] = ts;
    __syncthreads();
    if (tid < 4) {
        const int sL = tid;
        float v = 0.f; uint32_t cc = 0u;
#pragma unroll
        for (int w = 0; w < 8; ++w) { v += ls[sL][w]; cc += lc[sL][w]; }
        if (v != 0.f) atomicAdd(&gsum[sL*NBATCH + b], v);
        if (cc)       atomicAdd(&gcnt[sL*NBATCH + b], cc);
    }
    if (tid == 4) {
        float v = 0.f;
#pragma unroll
        for (int w = 0; w < 8; ++w) v += lt[w];
        if (v != 0.f) atomicAdd(&tsum[b], v);
    }
}

// ================= final combine =================
__global__ void k_final(const uint32_t* __restrict__ wu, const float* __restrict__ tsum,
                        const float* __restrict__ gsum, const uint32_t* __restrict__ gcnt,
                        float* __restrict__ out) {
    const int b = threadIdx.x;  // 64 threads, one wave
    uint32_t n2 = wu[ST_N2 + NBATCH + b];
    float v = n2 ? tsum[b] / (float)(2u*n2) : 0.f;
#pragma unroll
    for (int sL = 0; sL < 4; ++sL) {
        uint32_t cc = gcnt[sL*NBATCH + b];
        float g = cc ? gsum[sL*NBATCH + b] / (float)cc : 0.f;
        v += 0.5f * g;   // ALPHA = 0.5
    }
    for (int off = 32; off; off >>= 1) v += __shfl_down(v, off, 64);
    if (b == 0) out[0] = v * (1.f/64.f);
}

extern "C" void kernel_launch(void* const* d_in, const int* in_sizes, int n_in,
                              void* d_out, int out_size, void* d_ws, size_t ws_size,
                              hipStream_t stream) {
    const float* pred = (const float*)d_in[0];
    const float* tgt  = (const float*)d_in[1];
    uint32_t* wu = (uint32_t*)d_ws;
    float*    wf = (float*)d_ws;
    if (ws_size < (size_t)WS_TOTAL * 4) return;  // ~3.2 MB needed

    hipMemsetAsync(d_ws, 0, (size_t)WS_TOTAL * 4, stream);
    dim3 hg(HGX, NBATCH);

    // --- medians + analytic MAD scale (3-level radix select, sum-augmented level 3) ---
    k_medhist1<<<hg, 512, 0, stream>>>(pred, tgt, wu + OFF_C1, wf + ST_STOT);
    k_select<<<128, 256, 0, stream>>>(wu, wf, wu + OFF_C1, wf + OFF_SUM3, BINS1, 0);
    k_medhist2<<<hg, 512, 0, stream>>>(pred, tgt, wu + ST_B1, wu + OFF_C2, wf + ST_S1);
    k_select<<<128, 256, 0, stream>>>(wu, wf, wu + OFF_C2, wf + OFF_SUM3, BINS2, 1);
    k_medhist3<<<hg, 512, 0, stream>>>(pred, tgt, wu + ST_B1, wu + ST_B2, wu + OFF_C3,
                                       wf + OFF_SUM3, wf + ST_S2);
    k_select<<<128, 256, 0, stream>>>(wu, wf, wu + OFF_C3, wf + OFF_SUM3, BINS3, 2);

    // --- fused multiscale gradient loss + residual sum (tiled, dense, 512-thread, XCD-swizzled) ---
    k_grad<<<dim3(32, NBATCH), 512, 0, stream>>>(pred, tgt, wf + ST_SHIFT, wf + ST_SCL,
                                                 wf + ST_GSUM, wu + ST_GCNT, wf + ST_TSUM);
    // --- combine ---
    k_final<<<1, 64, 0, stream>>>(wu, wf + ST_TSUM, wf + ST_GSUM, wu + ST_GCNT, (float*)d_out);
}